// Round 1
// baseline (1277.479 us; speedup 1.0000x reference)
//
#include <hip/hip_runtime.h>
#include <hip/hip_bf16.h>

#define NEG_SLOPE 0.1f
#define BN_EPS 1e-5f

__device__ __forceinline__ float leaky(float x) { return x >= 0.0f ? x : NEG_SLOPE * x; }

// ---------------------------------------------------------------------------
// K2: scatter-add features into voxel sums + counts
// block = 256 threads = 4 rows x 64 cols
__global__ void k_down_scatter(const float* __restrict__ feat, const int* __restrict__ inv,
                               float* __restrict__ dsum, float* __restrict__ dcnt, int N) {
    int r = threadIdx.x >> 6;
    int c = threadIdx.x & 63;
    int row = blockIdx.x * 4 + r;
    if (row < N) {
        int v = inv[row];
        atomicAdd(&dsum[(size_t)v * 64 + c], feat[(size_t)row * 64 + c]);
        if (c == 0) atomicAdd(&dcnt[v], 1.0f);
    }
}

// ---------------------------------------------------------------------------
// K3/K5: out[M,64] = leaky(in[M,64] (/cnt) @ W[64,64] + bias[64]); accumulate col sums/sumsq
// block = 256 threads = 4 rows x 64 cols
__global__ void k_mlp64(const float* __restrict__ in, const float* __restrict__ cnt,
                        const float* __restrict__ W, const float* __restrict__ bias,
                        float* __restrict__ out, float* __restrict__ ssum, float* __restrict__ ssq,
                        int M) {
    __shared__ float a[4][64];
    __shared__ float t[4][64];
    int r = threadIdx.x >> 6;
    int c = threadIdx.x & 63;
    int row = blockIdx.x * 4 + r;
    float v = 0.0f;
    if (row < M) {
        v = in[(size_t)row * 64 + c];
        if (cnt) v /= fmaxf(cnt[row], 1.0f);
    }
    a[r][c] = v;
    __syncthreads();
    float acc = bias[c];
#pragma unroll
    for (int k = 0; k < 64; k++) acc = fmaf(a[r][k], W[k * 64 + c], acc);
    acc = leaky(acc);
    if (row < M) out[(size_t)row * 64 + c] = acc;
    t[r][c] = (row < M) ? acc : 0.0f;
    __syncthreads();
    if (r == 0) {
        float s = t[0][c] + t[1][c] + t[2][c] + t[3][c];
        float q = t[0][c] * t[0][c] + t[1][c] * t[1][c] + t[2][c] * t[2][c] + t[3][c] * t[3][c];
        atomicAdd(&ssum[c], s);
        atomicAdd(&ssq[c], q);
    }
}

// ---------------------------------------------------------------------------
// K4/K6: fold BatchNorm (from accumulated stats) into the next layer's weights:
// BN(x)_k = a_k x_k + c_k ;  Wp[k][j] = a_k W[k][j] ; bp[j] = b[j] + sum_k c_k W[k][j]
__global__ void k_fold(const float* __restrict__ ssum, const float* __restrict__ ssq,
                       const float* __restrict__ g, const float* __restrict__ be,
                       const float* __restrict__ W, const float* __restrict__ b,
                       float* __restrict__ Wp, float* __restrict__ bp, int M, int Cn) {
    int j = threadIdx.x;
    if (j >= Cn) return;
    float fM = (float)M;
    float accb = b[j];
    for (int k = 0; k < 64; k++) {
        float mu = ssum[k] / fM;
        float var = ssq[k] / fM - mu * mu;
        float rstd = rsqrtf(var + BN_EPS);
        float ak = g[k] * rstd;
        float ck = be[k] - mu * ak;
        float w = W[k * Cn + j];
        Wp[k * Cn + j] = ak * w;
        accb = fmaf(ck, w, accb);
    }
    bp[j] = accb;
}

// ---------------------------------------------------------------------------
// K7: out[M,128] = leaky(in[M,64] @ W[64,128] + bias[128])
// block = 256 threads = 2 rows x 128 cols
__global__ void k_mlp128(const float* __restrict__ in, const float* __restrict__ W,
                         const float* __restrict__ bias, float* __restrict__ out, int M) {
    __shared__ float a[2][64];
    int r = threadIdx.x >> 7;
    int c = threadIdx.x & 127;
    int row = blockIdx.x * 2 + r;
    if (c < 64) a[r][c] = (row < M) ? in[(size_t)row * 64 + c] : 0.0f;
    __syncthreads();
    if (row < M) {
        float acc = bias[c];
#pragma unroll
        for (int k = 0; k < 64; k++) acc = fmaf(a[r][k], W[k * 128 + c], acc);
        out[(size_t)row * 128 + c] = leaky(acc);
    }
}

// ---------------------------------------------------------------------------
// K8: outbuf[r, 0:128]   = leaky(features[r] @ W_in + b_in)
//     outbuf[r, 128:256] = h3[inv[r]]
// block = 256 threads = 2 rows x 128 cols
__global__ void k_identity_concat(const float* __restrict__ feat, const int* __restrict__ inv,
                                  const float* __restrict__ Win, const float* __restrict__ bin,
                                  const float* __restrict__ h3, float* __restrict__ outbuf, int N) {
    __shared__ float a[2][64];
    int r = threadIdx.x >> 7;
    int c = threadIdx.x & 127;
    int row = blockIdx.x * 2 + r;
    if (c < 64) a[r][c] = (row < N) ? feat[(size_t)row * 64 + c] : 0.0f;
    __syncthreads();
    if (row < N) {
        float acc = bin[c];
#pragma unroll
        for (int k = 0; k < 64; k++) acc = fmaf(a[r][k], Win[k * 128 + c], acc);
        outbuf[(size_t)row * 256 + c] = leaky(acc);
        outbuf[(size_t)row * 256 + 128 + c] = h3[(size_t)inv[row] * 128 + c];
    }
}

// ---------------------------------------------------------------------------
// K9: big fused layer: for each NF row i:
//   g = outbuf[cur[i]] (256) ; t = leaky(g@W4+b4) (128) ; o = t@W5+b5 (128)
//   atomic scatter-add o into vsum[nxt[i]], count into vcnt
// block = 128 threads (one col each), R=16 rows register-blocked
#define RBIG 16
__global__ __launch_bounds__(128) void k_big(const float* __restrict__ outbuf,
                                             const int* __restrict__ cur, const int* __restrict__ nxt,
                                             const float* __restrict__ W4, const float* __restrict__ b4,
                                             const float* __restrict__ W5, const float* __restrict__ b5,
                                             float* __restrict__ vsum, float* __restrict__ vcnt, int NF) {
    __shared__ float rows[RBIG][256];
    __shared__ float tmid[RBIG][128];
    int j = threadIdx.x;             // 0..127 output column
    int base = blockIdx.x * RBIG;
    // gather load RBIG rows: 2 rows per iteration, 64 threads per row, float4 each
    int rsub = j >> 6;               // 0..1
    int q = j & 63;                  // float4 index within row
    for (int rr = 0; rr < RBIG; rr += 2) {
        int r = rr + rsub;
        int idx = base + r;
        float4 v = make_float4(0.f, 0.f, 0.f, 0.f);
        if (idx < NF) {
            const float4* src = reinterpret_cast<const float4*>(outbuf + (size_t)cur[idx] * 256);
            v = src[q];
        }
        *reinterpret_cast<float4*>(&rows[r][q * 4]) = v;
    }
    __syncthreads();

    float acc[RBIG];
#pragma unroll
    for (int r = 0; r < RBIG; r++) acc[r] = b4[j];
    for (int k = 0; k < 256; k += 4) {
        float w0 = W4[(k + 0) * 128 + j];
        float w1 = W4[(k + 1) * 128 + j];
        float w2 = W4[(k + 2) * 128 + j];
        float w3 = W4[(k + 3) * 128 + j];
#pragma unroll
        for (int r = 0; r < RBIG; r++) {
            float4 a = *reinterpret_cast<const float4*>(&rows[r][k]);
            acc[r] = fmaf(a.x, w0, fmaf(a.y, w1, fmaf(a.z, w2, fmaf(a.w, w3, acc[r]))));
        }
    }
#pragma unroll
    for (int r = 0; r < RBIG; r++) tmid[r][j] = leaky(acc[r]);
    __syncthreads();

    float acc2[RBIG];
#pragma unroll
    for (int r = 0; r < RBIG; r++) acc2[r] = b5[j];
    for (int k = 0; k < 128; k += 4) {
        float w0 = W5[(k + 0) * 128 + j];
        float w1 = W5[(k + 1) * 128 + j];
        float w2 = W5[(k + 2) * 128 + j];
        float w3 = W5[(k + 3) * 128 + j];
#pragma unroll
        for (int r = 0; r < RBIG; r++) {
            float4 a = *reinterpret_cast<const float4*>(&tmid[r][k]);
            acc2[r] = fmaf(a.x, w0, fmaf(a.y, w1, fmaf(a.z, w2, fmaf(a.w, w3, acc2[r]))));
        }
    }
    for (int r = 0; r < RBIG; r++) {
        int idx = base + r;
        if (idx < NF) {
            int v = nxt[idx];
            atomicAdd(&vsum[(size_t)v * 128 + j], acc2[r]);
            if (j == 0) atomicAdd(&vcnt[v], 1.0f);
        }
    }
}

// ---------------------------------------------------------------------------
// K11: final divide
__global__ void k_final(const float* __restrict__ vsum, const float* __restrict__ vcnt,
                        float* __restrict__ out, int total) {
    int i = blockIdx.x * blockDim.x + threadIdx.x;
    if (i < total) {
        int m = i >> 7;
        out[i] = vsum[i] / fmaxf(vcnt[m], 1.0f);
    }
}

// ---------------------------------------------------------------------------
extern "C" void kernel_launch(void* const* d_in, const int* in_sizes, int n_in,
                              void* d_out, int out_size, void* d_ws, size_t ws_size,
                              hipStream_t stream) {
    const float* feat = (const float*)d_in[0];
    const int*   inv  = (const int*)d_in[1];
    const int*   cur  = (const int*)d_in[2];
    const int*   nxt  = (const int*)d_in[3];
    // d_in[4]=n_down, d_in[5]=n_out are device scalars; sizes are fixed by the problem
    const float* W_in = (const float*)d_in[6];
    const float* b_in = (const float*)d_in[7];
    const float* W1   = (const float*)d_in[8];
    const float* b1   = (const float*)d_in[9];
    const float* g1   = (const float*)d_in[10];
    const float* be1  = (const float*)d_in[11];
    const float* W2   = (const float*)d_in[12];
    const float* b2   = (const float*)d_in[13];
    const float* g2   = (const float*)d_in[14];
    const float* be2  = (const float*)d_in[15];
    const float* W3   = (const float*)d_in[16];
    const float* b3   = (const float*)d_in[17];
    const float* W4   = (const float*)d_in[18];
    const float* b4   = (const float*)d_in[19];
    const float* W5   = (const float*)d_in[20];
    const float* b5   = (const float*)d_in[21];

    const int N  = in_sizes[0] / 64;
    const int NF = in_sizes[2];
    const int MO = out_size / 128;
    const int MD = 25000;  // n_down (device scalar; fixed problem size)

    float* ws = (float*)d_ws;
    size_t off = 0;
    float* dsum  = ws + off; off += (size_t)MD * 64;
    float* dcnt  = ws + off; off += (size_t)MD;
    float* vsum  = ws + off; off += (size_t)MO * 128;
    float* vcnt  = ws + off; off += (size_t)MO;
    float* ssum1 = ws + off; off += 64;
    float* ssq1  = ws + off; off += 64;
    float* ssum2 = ws + off; off += 64;
    float* ssq2  = ws + off; off += 64;
    size_t zeroElems = off;
    float* t1   = ws + off; off += (size_t)MD * 64;
    float* t2   = ws + off; off += (size_t)MD * 64;
    float* h3   = ws + off; off += (size_t)MD * 128;
    float* Wp2  = ws + off; off += 64 * 64;
    float* bp2  = ws + off; off += 64;
    float* Wp3  = ws + off; off += 64 * 128;
    float* bp3  = ws + off; off += 128;
    float* outbuf = ws + off; off += (size_t)N * 256;
    (void)ws_size; (void)n_in;

    hipMemsetAsync(d_ws, 0, zeroElems * sizeof(float), stream);

    k_down_scatter<<<(N + 3) / 4, 256, 0, stream>>>(feat, inv, dsum, dcnt, N);
    k_mlp64<<<(MD + 3) / 4, 256, 0, stream>>>(dsum, dcnt, W1, b1, t1, ssum1, ssq1, MD);
    k_fold<<<1, 64, 0, stream>>>(ssum1, ssq1, g1, be1, W2, b2, Wp2, bp2, MD, 64);
    k_mlp64<<<(MD + 3) / 4, 256, 0, stream>>>(t1, nullptr, Wp2, bp2, t2, ssum2, ssq2, MD);
    k_fold<<<1, 128, 0, stream>>>(ssum2, ssq2, g2, be2, W3, b3, Wp3, bp3, MD, 128);
    k_mlp128<<<(MD + 1) / 2, 256, 0, stream>>>(t2, Wp3, bp3, h3, MD);
    k_identity_concat<<<(N + 1) / 2, 256, 0, stream>>>(feat, inv, W_in, b_in, h3, outbuf, N);
    k_big<<<(NF + RBIG - 1) / RBIG, 128, 0, stream>>>(outbuf, cur, nxt, W4, b4, W5, b5, vsum, vcnt, NF);
    k_final<<<(MO * 128 + 255) / 256, 256, 0, stream>>>(vsum, vcnt, (float*)d_out, MO * 128);
}

// Round 2
// 968.881 us; speedup vs baseline: 1.3185x; 1.3185x over previous
//
#include <hip/hip_runtime.h>
#include <hip/hip_bf16.h>

#define NEG_SLOPE 0.1f
#define BN_EPS 1e-5f

typedef __bf16 bf16_t;
typedef bf16_t bf16x8 __attribute__((ext_vector_type(8)));
typedef float f32x4 __attribute__((ext_vector_type(4)));

__device__ __forceinline__ float leaky(float x) { return x >= 0.0f ? x : NEG_SLOPE * x; }

// ---------------------------------------------------------------------------
// K2: scatter-add features into voxel sums + counts
__global__ void k_down_scatter(const float* __restrict__ feat, const int* __restrict__ inv,
                               float* __restrict__ dsum, float* __restrict__ dcnt, int N) {
    int r = threadIdx.x >> 6;
    int c = threadIdx.x & 63;
    int row = blockIdx.x * 4 + r;
    if (row < N) {
        int v = inv[row];
        atomicAdd(&dsum[(size_t)v * 64 + c], feat[(size_t)row * 64 + c]);
        if (c == 0) atomicAdd(&dcnt[v], 1.0f);
    }
}

// ---------------------------------------------------------------------------
// K3/K5: out[M,64] = leaky(in[M,64] (/cnt) @ W[64,64] + bias[64]); accumulate col stats
__global__ void k_mlp64(const float* __restrict__ in, const float* __restrict__ cnt,
                        const float* __restrict__ W, const float* __restrict__ bias,
                        float* __restrict__ out, float* __restrict__ ssum, float* __restrict__ ssq,
                        int M) {
    __shared__ float a[4][64];
    __shared__ float t[4][64];
    int r = threadIdx.x >> 6;
    int c = threadIdx.x & 63;
    int row = blockIdx.x * 4 + r;
    float v = 0.0f;
    if (row < M) {
        v = in[(size_t)row * 64 + c];
        if (cnt) v /= fmaxf(cnt[row], 1.0f);
    }
    a[r][c] = v;
    __syncthreads();
    float acc = bias[c];
#pragma unroll
    for (int k = 0; k < 64; k++) acc = fmaf(a[r][k], W[k * 64 + c], acc);
    acc = leaky(acc);
    if (row < M) out[(size_t)row * 64 + c] = acc;
    t[r][c] = (row < M) ? acc : 0.0f;
    __syncthreads();
    if (r == 0) {
        float s = t[0][c] + t[1][c] + t[2][c] + t[3][c];
        float q = t[0][c] * t[0][c] + t[1][c] * t[1][c] + t[2][c] * t[2][c] + t[3][c] * t[3][c];
        atomicAdd(&ssum[c], s);
        atomicAdd(&ssq[c], q);
    }
}

// ---------------------------------------------------------------------------
// K4/K6: fold BatchNorm into the next layer's weights
__global__ void k_fold(const float* __restrict__ ssum, const float* __restrict__ ssq,
                       const float* __restrict__ g, const float* __restrict__ be,
                       const float* __restrict__ W, const float* __restrict__ b,
                       float* __restrict__ Wp, float* __restrict__ bp, int M, int Cn) {
    int j = threadIdx.x;
    if (j >= Cn) return;
    float fM = (float)M;
    float accb = b[j];
    for (int k = 0; k < 64; k++) {
        float mu = ssum[k] / fM;
        float var = ssq[k] / fM - mu * mu;
        float rstd = rsqrtf(var + BN_EPS);
        float ak = g[k] * rstd;
        float ck = be[k] - mu * ak;
        float w = W[k * Cn + j];
        Wp[k * Cn + j] = ak * w;
        accb = fmaf(ck, w, accb);
    }
    bp[j] = accb;
}

// ---------------------------------------------------------------------------
// K7: h3 (bf16) = leaky(in[M,64] @ W[64,128] + bias)
__global__ void k_mlp128(const float* __restrict__ in, const float* __restrict__ W,
                         const float* __restrict__ bias, bf16_t* __restrict__ out, int M) {
    __shared__ float a[2][64];
    int r = threadIdx.x >> 7;
    int c = threadIdx.x & 127;
    int row = blockIdx.x * 2 + r;
    if (c < 64) a[r][c] = (row < M) ? in[(size_t)row * 64 + c] : 0.0f;
    __syncthreads();
    if (row < M) {
        float acc = bias[c];
#pragma unroll
        for (int k = 0; k < 64; k++) acc = fmaf(a[r][k], W[k * 128 + c], acc);
        out[(size_t)row * 128 + c] = (bf16_t)leaky(acc);
    }
}

// ---------------------------------------------------------------------------
// K8: outbuf (bf16) [N,256] = [leaky(feat@W_in+b_in) , h3[inv]]
__global__ void k_identity_concat(const float* __restrict__ feat, const int* __restrict__ inv,
                                  const float* __restrict__ Win, const float* __restrict__ bin,
                                  const bf16_t* __restrict__ h3, bf16_t* __restrict__ outbuf, int N) {
    __shared__ float a[2][64];
    int r = threadIdx.x >> 7;
    int c = threadIdx.x & 127;
    int row = blockIdx.x * 2 + r;
    if (c < 64) a[r][c] = (row < N) ? feat[(size_t)row * 64 + c] : 0.0f;
    __syncthreads();
    if (row < N) {
        float acc = bin[c];
#pragma unroll
        for (int k = 0; k < 64; k++) acc = fmaf(a[r][k], Win[k * 128 + c], acc);
        outbuf[(size_t)row * 256 + c] = (bf16_t)leaky(acc);
        outbuf[(size_t)row * 256 + 128 + c] = h3[(size_t)inv[row] * 128 + c];
    }
}

// ---------------------------------------------------------------------------
// Pack W4/W5 (fp32 row-major [K,128]) into bf16 MFMA-B fragment order:
// P[((s*8+n)*64+l)*8+j] = W[(s*32+(l>>4)*8+j)][n*16+(l&15)]
__global__ void k_pack(const float* __restrict__ W4, const float* __restrict__ W5,
                       bf16_t* __restrict__ P1, bf16_t* __restrict__ P2) {
    int tid = blockIdx.x * 256 + threadIdx.x;
    if (tid < 4096) {
        int l = tid & 63;
        int sn = tid >> 6;
        int col = (sn & 7) * 16 + (l & 15);
        int k0 = (sn >> 3) * 32 + (l >> 4) * 8;
        bf16_t* dst = P1 + (size_t)tid * 8;
#pragma unroll
        for (int j = 0; j < 8; j++) dst[j] = (bf16_t)W4[(size_t)(k0 + j) * 128 + col];
    } else if (tid < 6144) {
        int t = tid - 4096;
        int l = t & 63;
        int sn = t >> 6;
        int col = (sn & 7) * 16 + (l & 15);
        int k0 = (sn >> 3) * 32 + (l >> 4) * 8;
        bf16_t* dst = P2 + (size_t)t * 8;
#pragma unroll
        for (int j = 0; j < 8; j++) dst[j] = (bf16_t)W5[(size_t)(k0 + j) * 128 + col];
    }
}

// ---------------------------------------------------------------------------
// K9: MFMA fused layer. 256 thr = 4 waves; 64 gathered rows/block.
// GEMM1 [64,256]@[256,128] -> leaky -> bf16 Mid -> GEMM2 [64,128]@[128,128] -> atomic scatter.
// LDS XOR swizzle (elem ^= (row&7)<<3) breaks the 16-way bank conflict of
// 512B/256B row strides on ds_read_b128 (guide §6 G4).
#define RB 64
__global__ __launch_bounds__(256) void k_big_mfma(
        const bf16_t* __restrict__ outb,
        const int* __restrict__ cur, const int* __restrict__ nxt,
        const bf16_t* __restrict__ P1, const bf16_t* __restrict__ P2,
        const float* __restrict__ b4, const float* __restrict__ b5,
        float* __restrict__ vsum, float* __restrict__ vcnt, int NF) {
    __shared__ bf16_t Atile[64 * 256];
    __shared__ bf16_t Mid[64 * 128];
    __shared__ int curIdx[64];
    __shared__ int nxtIdx[64];
    int tid = threadIdx.x;
    int base = blockIdx.x * RB;
    if (tid < 64) curIdx[tid] = (base + tid < NF) ? cur[base + tid] : -1;
    else if (tid < 128) nxtIdx[tid - 64] = (base + tid - 64 < NF) ? nxt[base + tid - 64] : 0;
    __syncthreads();

    // gather-stage 64 rows x 512B: 32 threads/row, float4 each
    int q = tid & 31;
    int r0 = tid >> 5;
#pragma unroll
    for (int p = 0; p < 8; p++) {
        int r = p * 8 + r0;
        int cidx = curIdx[r];
        float4 v = make_float4(0.f, 0.f, 0.f, 0.f);
        if (cidx >= 0) v = reinterpret_cast<const float4*>(outb + (size_t)cidx * 256)[q];
        *reinterpret_cast<float4*>(&Atile[r * 256 + ((q * 8) ^ ((r & 7) << 3))]) = v;
    }
    __syncthreads();

    int w = tid >> 6, l = tid & 63;
    int lg = l >> 4, lr = l & 15;
    int rowA = w * 16 + lr;
    int xa = (rowA & 7) << 3;

    // GEMM1: K=256, 8 k-steps, 8 col-tiles
    f32x4 acc[8];
#pragma unroll
    for (int n = 0; n < 8; n++) { float bv = b4[n * 16 + lr]; acc[n] = (f32x4){bv, bv, bv, bv}; }
#pragma unroll
    for (int s = 0; s < 8; s++) {
        bf16x8 a = *reinterpret_cast<const bf16x8*>(&Atile[rowA * 256 + (((s * 4 + lg) * 8) ^ xa)]);
#pragma unroll
        for (int n = 0; n < 8; n++) {
            bf16x8 b = *reinterpret_cast<const bf16x8*>(P1 + ((size_t)(s * 8 + n) * 64 + l) * 8);
            acc[n] = __builtin_amdgcn_mfma_f32_16x16x32_bf16(a, b, acc[n], 0, 0, 0);
        }
    }

    // leaky -> bf16 -> Mid (wave-private rows; swizzled)
#pragma unroll
    for (int n = 0; n < 8; n++) {
#pragma unroll
        for (int rr = 0; rr < 4; rr++) {
            int row = w * 16 + lg * 4 + rr;
            int col = n * 16 + lr;
            Mid[row * 128 + (col ^ ((row & 7) << 3))] = (bf16_t)leaky(acc[n][rr]);
        }
    }

    // GEMM2: K=128, 4 k-steps (wave reads only its own Mid rows; no barrier needed)
    f32x4 acc2[8];
#pragma unroll
    for (int n = 0; n < 8; n++) { float bv = b5[n * 16 + lr]; acc2[n] = (f32x4){bv, bv, bv, bv}; }
#pragma unroll
    for (int s = 0; s < 4; s++) {
        bf16x8 a = *reinterpret_cast<const bf16x8*>(&Mid[rowA * 128 + ((s * 32 + lg * 8) ^ xa)]);
#pragma unroll
        for (int n = 0; n < 8; n++) {
            bf16x8 b = *reinterpret_cast<const bf16x8*>(P2 + ((size_t)(s * 8 + n) * 64 + l) * 8);
            acc2[n] = __builtin_amdgcn_mfma_f32_16x16x32_bf16(a, b, acc2[n], 0, 0, 0);
        }
    }

    // scatter: D row = w*16 + lg*4 + rr, col = n*16 + lr
#pragma unroll
    for (int rr = 0; rr < 4; rr++) {
        int rloc = w * 16 + lg * 4 + rr;
        int g = base + rloc;
        if (g < NF) {
            int v = nxtIdx[rloc];
            float* dst = vsum + (size_t)v * 128;
#pragma unroll
            for (int n = 0; n < 8; n++) atomicAdd(dst + n * 16 + lr, acc2[n][rr]);
            if (lr == 0) atomicAdd(vcnt + v, 1.0f);
        }
    }
}

// ---------------------------------------------------------------------------
// K11: final divide
__global__ void k_final(const float* __restrict__ vsum, const float* __restrict__ vcnt,
                        float* __restrict__ out, int total) {
    int i = blockIdx.x * blockDim.x + threadIdx.x;
    if (i < total) {
        int m = i >> 7;
        out[i] = vsum[i] / fmaxf(vcnt[m], 1.0f);
    }
}

// ---------------------------------------------------------------------------
extern "C" void kernel_launch(void* const* d_in, const int* in_sizes, int n_in,
                              void* d_out, int out_size, void* d_ws, size_t ws_size,
                              hipStream_t stream) {
    const float* feat = (const float*)d_in[0];
    const int*   inv  = (const int*)d_in[1];
    const int*   cur  = (const int*)d_in[2];
    const int*   nxt  = (const int*)d_in[3];
    const float* W_in = (const float*)d_in[6];
    const float* b_in = (const float*)d_in[7];
    const float* W1   = (const float*)d_in[8];
    const float* b1   = (const float*)d_in[9];
    const float* g1   = (const float*)d_in[10];
    const float* be1  = (const float*)d_in[11];
    const float* W2   = (const float*)d_in[12];
    const float* b2   = (const float*)d_in[13];
    const float* g2   = (const float*)d_in[14];
    const float* be2  = (const float*)d_in[15];
    const float* W3   = (const float*)d_in[16];
    const float* b3   = (const float*)d_in[17];
    const float* W4   = (const float*)d_in[18];
    const float* b4   = (const float*)d_in[19];
    const float* W5   = (const float*)d_in[20];
    const float* b5   = (const float*)d_in[21];

    const int N  = in_sizes[0] / 64;
    const int NF = in_sizes[2];
    const int MO = out_size / 128;
    const int MD = 25000;  // n_down (device scalar; fixed problem size)

    float* ws = (float*)d_ws;
    size_t off = 0;
    float* dsum  = ws + off; off += (size_t)MD * 64;
    float* dcnt  = ws + off; off += (size_t)MD;
    float* vsum  = ws + off; off += (size_t)MO * 128;
    float* vcnt  = ws + off; off += (size_t)MO;
    float* ssum1 = ws + off; off += 64;
    float* ssq1  = ws + off; off += 64;
    float* ssum2 = ws + off; off += 64;
    float* ssq2  = ws + off; off += 64;
    size_t zeroElems = off;
    float* t1   = ws + off; off += (size_t)MD * 64;
    float* t2   = ws + off; off += (size_t)MD * 64;
    float* Wp2  = ws + off; off += 64 * 64;
    float* bp2  = ws + off; off += 64;
    float* Wp3  = ws + off; off += 64 * 128;
    float* bp3  = ws + off; off += 128;
    bf16_t* bws = (bf16_t*)(ws + off);
    size_t boff = 0;
    bf16_t* h3b  = bws + boff; boff += (size_t)MD * 128;
    bf16_t* outb = bws + boff; boff += (size_t)N * 256;
    bf16_t* P1   = bws + boff; boff += 32768;
    bf16_t* P2   = bws + boff; boff += 16384;
    (void)ws_size; (void)n_in;

    hipMemsetAsync(d_ws, 0, zeroElems * sizeof(float), stream);

    k_down_scatter<<<(N + 3) / 4, 256, 0, stream>>>(feat, inv, dsum, dcnt, N);
    k_mlp64<<<(MD + 3) / 4, 256, 0, stream>>>(dsum, dcnt, W1, b1, t1, ssum1, ssq1, MD);
    k_fold<<<1, 64, 0, stream>>>(ssum1, ssq1, g1, be1, W2, b2, Wp2, bp2, MD, 64);
    k_mlp64<<<(MD + 3) / 4, 256, 0, stream>>>(t1, nullptr, Wp2, bp2, t2, ssum2, ssq2, MD);
    k_fold<<<1, 128, 0, stream>>>(ssum2, ssq2, g2, be2, W3, b3, Wp3, bp3, MD, 128);
    k_mlp128<<<(MD + 1) / 2, 256, 0, stream>>>(t2, Wp3, bp3, h3b, MD);
    k_identity_concat<<<(N + 1) / 2, 256, 0, stream>>>(feat, inv, W_in, b_in, h3b, outb, N);
    k_pack<<<24, 256, 0, stream>>>(W4, W5, P1, P2);
    k_big_mfma<<<(NF + RB - 1) / RB, 256, 0, stream>>>(outb, cur, nxt, P1, P2, b4, b5, vsum, vcnt, NF);
    k_final<<<(MO * 128 + 255) / 256, 256, 0, stream>>>(vsum, vcnt, (float*)d_out, MO * 128);
}

// Round 5
// 594.074 us; speedup vs baseline: 2.1504x; 1.6309x over previous
//
#include <hip/hip_runtime.h>
#include <hip/hip_bf16.h>

#define NEG_SLOPE 0.1f
#define BN_EPS 1e-5f
#define MDV 25000
#define CHUNK_CAP 50016   // >= MO + NF/16 upper bound on total 16-row chunks

typedef __bf16 bf16_t;
typedef bf16_t bf16x8 __attribute__((ext_vector_type(8)));
typedef float f32x4 __attribute__((ext_vector_type(4)));

__device__ __forceinline__ float leaky(float x) { return x >= 0.0f ? x : NEG_SLOPE * x; }

// ---------------------------------------------------------------------------
// scatter-add features into voxel sums + counts
__global__ void k_down_scatter(const float* __restrict__ feat, const int* __restrict__ inv,
                               float* __restrict__ dsum, float* __restrict__ dcnt, int N) {
    int r = threadIdx.x >> 6;
    int c = threadIdx.x & 63;
    int row = blockIdx.x * 4 + r;
    if (row < N) {
        int v = inv[row];
        atomicAdd(&dsum[(size_t)v * 64 + c], feat[(size_t)row * 64 + c]);
        if (c == 0) atomicAdd(&dcnt[v], 1.0f);
    }
}

// ---------------------------------------------------------------------------
// grid-stride MLP64 + BN stats (one atomic per column per block: low contention)
__global__ __launch_bounds__(256) void k_mlp64(
        const float* __restrict__ in, const float* __restrict__ cnt,
        const float* __restrict__ W, const float* __restrict__ bias,
        float* __restrict__ out, float* __restrict__ ssum, float* __restrict__ ssq, int M) {
    __shared__ float a[4][64];
    int r = threadIdx.x >> 6;
    int c = threadIdx.x & 63;
    int ntiles = (M + 3) / 4;
    float ls = 0.0f, lq = 0.0f;
    for (int tile = blockIdx.x; tile < ntiles; tile += gridDim.x) {
        int row = tile * 4 + r;
        float v = 0.0f;
        if (row < M) {
            v = in[(size_t)row * 64 + c];
            if (cnt) v /= fmaxf(cnt[row], 1.0f);
        }
        __syncthreads();
        a[r][c] = v;
        __syncthreads();
        float acc = bias[c];
#pragma unroll
        for (int k = 0; k < 64; k++) acc = fmaf(a[r][k], W[k * 64 + c], acc);
        acc = leaky(acc);
        if (row < M) {
            out[(size_t)row * 64 + c] = acc;
            ls += acc;
            lq += acc * acc;
        }
    }
    __syncthreads();
    a[r][c] = ls;
    __syncthreads();
    if (r == 0) atomicAdd(&ssum[c], a[0][c] + a[1][c] + a[2][c] + a[3][c]);
    __syncthreads();
    a[r][c] = lq;
    __syncthreads();
    if (r == 0) atomicAdd(&ssq[c], a[0][c] + a[1][c] + a[2][c] + a[3][c]);
}

// ---------------------------------------------------------------------------
// fold BatchNorm into the next layer's weights
__global__ void k_fold(const float* __restrict__ ssum, const float* __restrict__ ssq,
                       const float* __restrict__ g, const float* __restrict__ be,
                       const float* __restrict__ W, const float* __restrict__ b,
                       float* __restrict__ Wp, float* __restrict__ bp, int M, int Cn) {
    int j = threadIdx.x;
    if (j >= Cn) return;
    float fM = (float)M;
    float accb = b[j];
    for (int k = 0; k < 64; k++) {
        float mu = ssum[k] / fM;
        float var = ssq[k] / fM - mu * mu;
        float rstd = rsqrtf(var + BN_EPS);
        float ak = g[k] * rstd;
        float ck = be[k] - mu * ak;
        float w = W[k * Cn + j];
        Wp[k * Cn + j] = ak * w;
        accb = fmaf(ck, w, accb);
    }
    bp[j] = accb;
}

// ---------------------------------------------------------------------------
// h3 (bf16) = leaky(in[M,64] @ W[64,128] + bias)
__global__ void k_mlp128(const float* __restrict__ in, const float* __restrict__ W,
                         const float* __restrict__ bias, bf16_t* __restrict__ out, int M) {
    __shared__ float a[2][64];
    int r = threadIdx.x >> 7;
    int c = threadIdx.x & 127;
    int row = blockIdx.x * 2 + r;
    if (c < 64) a[r][c] = (row < M) ? in[(size_t)row * 64 + c] : 0.0f;
    __syncthreads();
    if (row < M) {
        float acc = bias[c];
#pragma unroll
        for (int k = 0; k < 64; k++) acc = fmaf(a[r][k], W[k * 128 + c], acc);
        out[(size_t)row * 128 + c] = (bf16_t)leaky(acc);
    }
}

// ---------------------------------------------------------------------------
// outbuf (bf16) [N,256] = [leaky(feat@W_in+b_in) , h3[inv]]
__global__ void k_identity_concat(const float* __restrict__ feat, const int* __restrict__ inv,
                                  const float* __restrict__ Win, const float* __restrict__ bin,
                                  const bf16_t* __restrict__ h3, bf16_t* __restrict__ outbuf, int N) {
    __shared__ float a[2][64];
    int r = threadIdx.x >> 7;
    int c = threadIdx.x & 127;
    int row = blockIdx.x * 2 + r;
    if (c < 64) a[r][c] = (row < N) ? feat[(size_t)row * 64 + c] : 0.0f;
    __syncthreads();
    if (row < N) {
        float acc = bin[c];
#pragma unroll
        for (int k = 0; k < 64; k++) acc = fmaf(a[r][k], Win[k * 128 + c], acc);
        outbuf[(size_t)row * 256 + c] = (bf16_t)leaky(acc);
        outbuf[(size_t)row * 256 + 128 + c] = h3[(size_t)inv[row] * 128 + c];
    }
}

// ---------------------------------------------------------------------------
// Pack W4/W5 (fp32 row-major [K,128]) into bf16 MFMA-B fragment order:
// P[((s*8+n)*64+l)*8+j] = W[(s*32+(l>>4)*8+j)][n*16+(l&15)]
__global__ void k_pack(const float* __restrict__ W4, const float* __restrict__ W5,
                       bf16_t* __restrict__ P1, bf16_t* __restrict__ P2) {
    int tid = blockIdx.x * 256 + threadIdx.x;
    if (tid < 4096) {
        int l = tid & 63;
        int sn = tid >> 6;
        int col = (sn & 7) * 16 + (l & 15);
        int k0 = (sn >> 3) * 32 + (l >> 4) * 8;
        bf16_t* dst = P1 + (size_t)tid * 8;
#pragma unroll
        for (int j = 0; j < 8; j++) dst[j] = (bf16_t)W4[(size_t)(k0 + j) * 128 + col];
    } else if (tid < 6144) {
        int t = tid - 4096;
        int l = t & 63;
        int sn = t >> 6;
        int col = (sn & 7) * 16 + (l & 15);
        int k0 = (sn >> 3) * 32 + (l >> 4) * 8;
        bf16_t* dst = P2 + (size_t)t * 8;
#pragma unroll
        for (int j = 0; j < 8; j++) dst[j] = (bf16_t)W5[(size_t)(k0 + j) * 128 + col];
    }
}

// ---------------------------------------------------------------------------
// CSR build: histogram over nxt
__global__ void k_hist(const int* __restrict__ nxt, int* __restrict__ cntI, int NF) {
    int f = blockIdx.x * 256 + threadIdx.x;
    if (f < NF) atomicAdd(&cntI[nxt[f]], 1);
}

// dual exclusive scan (cnt and ceil(cnt/16)) over M entries, single block of 1024
__global__ void k_scan(const int* __restrict__ cntI, int* __restrict__ rowstart,
                       int* __restrict__ chunkbase, int M) {
    __shared__ int sA[1024], sB[1024], sA2[1024], sB2[1024];
    int t = threadIdx.x;
    int carry1 = 0, carry2 = 0;
    for (int base = 0; base < M; base += 1024) {
        int i = base + t;
        int c = (i < M) ? cntI[i] : 0;
        int h = (c + 15) >> 4;
        sA[t] = c; sA2[t] = h;
        __syncthreads();
        int* src = sA; int* dst = sB; int* src2 = sA2; int* dst2 = sB2;
        for (int off = 1; off < 1024; off <<= 1) {
            int v1 = src[t] + ((t >= off) ? src[t - off] : 0);
            int v2 = src2[t] + ((t >= off) ? src2[t - off] : 0);
            dst[t] = v1; dst2[t] = v2;
            __syncthreads();
            int* tmp = src; src = dst; dst = tmp;
            tmp = src2; src2 = dst2; dst2 = tmp;
        }
        if (i < M) {
            rowstart[i] = carry1 + src[t] - c;
            chunkbase[i] = carry2 + src2[t] - h;
        }
        carry1 += src[1023];
        carry2 += src2[1023];
        __syncthreads();
    }
    if (t == 0) { rowstart[M] = carry1; chunkbase[M] = carry2; }
}

// fill CSR row lists; store the GATHER row (cur[f]) directly
__global__ void k_fill(const int* __restrict__ nxt, const int* __restrict__ cur,
                       const int* __restrict__ rowstart, int* __restrict__ cursor,
                       int* __restrict__ csr, int NF) {
    int f = blockIdx.x * 256 + threadIdx.x;
    if (f < NF) {
        int v = nxt[f];
        int pos = atomicAdd(&cursor[v], 1);
        csr[rowstart[v] + pos] = cur[f];
    }
}

// build fixed 16-row chunk list; zero-len the tail beyond NC
__global__ void k_chunkfill(const int* __restrict__ cntI, const int* __restrict__ rowstart,
                            const int* __restrict__ chunkbase,
                            int* __restrict__ chv, int* __restrict__ choff, int* __restrict__ chlen,
                            int M, int cap) {
    int tid = blockIdx.x * 256 + threadIdx.x;
    int NC = chunkbase[M];
    if (tid < M) {
        int nf = cntI[tid];
        int nch = (nf + 15) >> 4;
        int cb = chunkbase[tid];
        int rs = rowstart[tid];
        for (int j = 0; j < nch; j++) {
            chv[cb + j] = tid;
            choff[cb + j] = rs + j * 16;
            chlen[cb + j] = min(16, nf - j * 16);
        }
    }
    if (tid >= NC && tid < cap) chlen[tid] = 0;
}

// ---------------------------------------------------------------------------
// k_voxel: block = 4 chunks (64 rows), 4 waves split the 128 output columns
// (wave w owns cols [w*32,w*32+32)): P1/P2 read ONCE per block.
// gather A rows -> LDS (swizzled) -> GEMM1 -> Mid (aliased over Atile) ->
// GEMM2 -> masked row-sum per chunk -> one 16-lane atomic per (chunk, 16 cols).
__global__ __launch_bounds__(256) void k_voxel(
        const bf16_t* __restrict__ outb, const int* __restrict__ csr,
        const int* __restrict__ chv, const int* __restrict__ choff, const int* __restrict__ chlen,
        const bf16_t* __restrict__ P1, const bf16_t* __restrict__ P2,
        const float* __restrict__ b4, float* __restrict__ vsum) {
    __shared__ bf16_t Atile[64 * 256];   // 32KB; Mid[64*128] aliases the first 16KB
    bf16_t* Mid = Atile;
    __shared__ int ridx[64];
    __shared__ int mv[4], mlen[4];
    __shared__ int moff[4];

    int tid = threadIdx.x;
    int basec = blockIdx.x * 4;
    if (tid < 4) {
        mv[tid] = chv[basec + tid];
        moff[tid] = choff[basec + tid];
        mlen[tid] = chlen[basec + tid];
    }
    __syncthreads();
    if (mlen[0] + mlen[1] + mlen[2] + mlen[3] == 0) return;   // uniform exit

    if (tid < 64) {
        int m = tid >> 4, r = tid & 15;
        ridx[tid] = (r < mlen[m]) ? csr[moff[m] + r] : -1;
    }
    __syncthreads();

    // gather 64 rows x 512B: 4 threads/row, 8 float4 each
    {
        int row = tid >> 2;
        int cid = ridx[row];
        int xa = (row & 7) << 3;
#pragma unroll
        for (int j = 0; j < 8; j++) {
            int q = (tid & 3) + 4 * j;
            float4 val = make_float4(0.f, 0.f, 0.f, 0.f);
            if (cid >= 0) val = reinterpret_cast<const float4*>(outb + (size_t)cid * 256)[q];
            *reinterpret_cast<float4*>(&Atile[row * 256 + ((q * 8) ^ xa)]) = val;
        }
    }
    __syncthreads();

    int w = tid >> 6, l = tid & 63;
    int lg = l >> 4, lr = l & 15;
    int xr = (lr & 7) << 3;   // read-row swizzle (row = m*16+lr, m*16 is 0 mod 8)

    // GEMM1: K=256 (8 k-steps), per wave 2 n-tiles, 4 m-tiles
    f32x4 acc1[4][2];
#pragma unroll
    for (int t = 0; t < 2; t++) {
        float bv = b4[w * 32 + t * 16 + lr];
#pragma unroll
        for (int m = 0; m < 4; m++) acc1[m][t] = (f32x4){bv, bv, bv, bv};
    }
#pragma unroll
    for (int s = 0; s < 8; s++) {
        bf16x8 a[4];
#pragma unroll
        for (int m = 0; m < 4; m++)
            a[m] = *reinterpret_cast<const bf16x8*>(&Atile[(m * 16 + lr) * 256 + (((s * 4 + lg) * 8) ^ xr)]);
#pragma unroll
        for (int t = 0; t < 2; t++) {
            bf16x8 b = *reinterpret_cast<const bf16x8*>(P1 + ((size_t)(s * 8 + w * 2 + t) * 64 + l) * 8);
#pragma unroll
            for (int m = 0; m < 4; m++)
                acc1[m][t] = __builtin_amdgcn_mfma_f32_16x16x32_bf16(a[m], b, acc1[m][t], 0, 0, 0);
        }
    }
    __syncthreads();   // all GEMM1 Atile reads complete before Mid overwrites

    // Mid = leaky(acc1) bf16, swizzled
#pragma unroll
    for (int m = 0; m < 4; m++) {
#pragma unroll
        for (int t = 0; t < 2; t++) {
#pragma unroll
            for (int rr = 0; rr < 4; rr++) {
                int row = m * 16 + lg * 4 + rr;
                int col = w * 32 + t * 16 + lr;
                Mid[row * 128 + (col ^ ((row & 7) << 3))] = (bf16_t)leaky(acc1[m][t][rr]);
            }
        }
    }
    __syncthreads();

    // GEMM2: K=128 (4 k-steps)
    f32x4 acc2[4][2];
#pragma unroll
    for (int t = 0; t < 2; t++)
#pragma unroll
        for (int m = 0; m < 4; m++) acc2[m][t] = (f32x4){0.f, 0.f, 0.f, 0.f};
#pragma unroll
    for (int s = 0; s < 4; s++) {
        bf16x8 a[4];
#pragma unroll
        for (int m = 0; m < 4; m++)
            a[m] = *reinterpret_cast<const bf16x8*>(&Mid[(m * 16 + lr) * 128 + ((s * 32 + lg * 8) ^ xr)]);
#pragma unroll
        for (int t = 0; t < 2; t++) {
            bf16x8 b = *reinterpret_cast<const bf16x8*>(P2 + ((size_t)(s * 8 + w * 2 + t) * 64 + l) * 8);
#pragma unroll
            for (int m = 0; m < 4; m++)
                acc2[m][t] = __builtin_amdgcn_mfma_f32_16x16x32_bf16(a[m], b, acc2[m][t], 0, 0, 0);
        }
    }

    // masked row-sum per chunk, butterfly over lg, one atomic per (chunk, 16 lanes)
#pragma unroll
    for (int m = 0; m < 4; m++) {
        int len = mlen[m];
        if (len == 0) continue;   // uniform across block
#pragma unroll
        for (int t = 0; t < 2; t++) {
            float s = 0.0f;
#pragma unroll
            for (int rr = 0; rr < 4; rr++) {
                int r = lg * 4 + rr;
                if (r < len) s += acc2[m][t][rr];
            }
            s += __shfl_xor(s, 16);
            s += __shfl_xor(s, 32);
            if (lg == 0) atomicAdd(&vsum[(size_t)mv[m] * 128 + w * 32 + t * 16 + lr], s);
        }
    }
}

// ---------------------------------------------------------------------------
// final: out = vsum/cnt + b5 (0 where cnt==0)
__global__ void k_final(const float* __restrict__ vsum, const int* __restrict__ cntI,
                        const float* __restrict__ b5, float* __restrict__ out, int total) {
    int i = blockIdx.x * blockDim.x + threadIdx.x;
    if (i < total) {
        int m = i >> 7;
        int nf = cntI[m];
        out[i] = (nf > 0) ? (vsum[i] / (float)nf + b5[i & 127]) : 0.0f;
    }
}

// ---------------------------------------------------------------------------
extern "C" void kernel_launch(void* const* d_in, const int* in_sizes, int n_in,
                              void* d_out, int out_size, void* d_ws, size_t ws_size,
                              hipStream_t stream) {
    const float* feat = (const float*)d_in[0];
    const int*   inv  = (const int*)d_in[1];
    const int*   cur  = (const int*)d_in[2];
    const int*   nxt  = (const int*)d_in[3];
    const float* W_in = (const float*)d_in[6];
    const float* b_in = (const float*)d_in[7];
    const float* W1   = (const float*)d_in[8];
    const float* b1   = (const float*)d_in[9];
    const float* g1   = (const float*)d_in[10];
    const float* be1  = (const float*)d_in[11];
    const float* W2   = (const float*)d_in[12];
    const float* b2   = (const float*)d_in[13];
    const float* g2   = (const float*)d_in[14];
    const float* be2  = (const float*)d_in[15];
    const float* W3   = (const float*)d_in[16];
    const float* b3   = (const float*)d_in[17];
    const float* W4   = (const float*)d_in[18];
    const float* b4   = (const float*)d_in[19];
    const float* W5   = (const float*)d_in[20];
    const float* b5   = (const float*)d_in[21];

    const int N  = in_sizes[0] / 64;
    const int NF = in_sizes[2];
    const int MO = out_size / 128;
    const int MD = MDV;   // n_down (device scalar; fixed problem size)

    float* ws = (float*)d_ws;
    size_t off = 0;
    // ---- zeroed region ----
    float* dsum  = ws + off; off += (size_t)MD * 64;
    float* dcnt  = ws + off; off += (size_t)MD;
    float* vsum  = ws + off; off += (size_t)MO * 128;
    float* ssum1 = ws + off; off += 64;
    float* ssq1  = ws + off; off += 64;
    float* ssum2 = ws + off; off += 64;
    float* ssq2  = ws + off; off += 64;
    int* cntI    = (int*)(ws + off); off += (size_t)MO;
    int* cursor  = (int*)(ws + off); off += (size_t)MO;
    size_t zeroElems = off;
    // ---- non-zeroed ----
    float* t1   = ws + off; off += (size_t)MD * 64;
    float* t2   = ws + off; off += (size_t)MD * 64;
    float* Wp2  = ws + off; off += 64 * 64;
    float* bp2  = ws + off; off += 64;
    float* Wp3  = ws + off; off += 64 * 128;
    float* bp3  = ws + off; off += 128;
    int* rowstart  = (int*)(ws + off); off += (size_t)MO + 1;
    int* chunkbase = (int*)(ws + off); off += (size_t)MO + 1;
    int* csr       = (int*)(ws + off); off += (size_t)NF;
    int* chv       = (int*)(ws + off); off += CHUNK_CAP;
    int* choff     = (int*)(ws + off); off += CHUNK_CAP;
    int* chlen     = (int*)(ws + off); off += CHUNK_CAP;
    bf16_t* bws = (bf16_t*)(ws + off);
    size_t boff = 0;
    bf16_t* h3b  = bws + boff; boff += (size_t)MD * 128;
    bf16_t* outb = bws + boff; boff += (size_t)N * 256;
    bf16_t* P1   = bws + boff; boff += 32768;
    bf16_t* P2   = bws + boff; boff += 16384;
    (void)ws_size; (void)n_in;

    hipMemsetAsync(d_ws, 0, zeroElems * sizeof(float), stream);

    // front MLP path
    k_down_scatter<<<(N + 3) / 4, 256, 0, stream>>>(feat, inv, dsum, dcnt, N);
    k_mlp64<<<128, 256, 0, stream>>>(dsum, dcnt, W1, b1, t1, ssum1, ssq1, MD);
    k_fold<<<1, 64, 0, stream>>>(ssum1, ssq1, g1, be1, W2, b2, Wp2, bp2, MD, 64);
    k_mlp64<<<128, 256, 0, stream>>>(t1, nullptr, Wp2, bp2, t2, ssum2, ssq2, MD);
    k_fold<<<1, 128, 0, stream>>>(ssum2, ssq2, g2, be2, W3, b3, Wp3, bp3, MD, 128);
    k_mlp128<<<(MD + 1) / 2, 256, 0, stream>>>(t2, Wp3, bp3, h3b, MD);
    k_identity_concat<<<(N + 1) / 2, 256, 0, stream>>>(feat, inv, W_in, b_in, h3b, outb, N);
    k_pack<<<24, 256, 0, stream>>>(W4, W5, P1, P2);

    // CSR over nxt (csr stores gather rows cur[f])
    k_hist<<<(NF + 255) / 256, 256, 0, stream>>>(nxt, cntI, NF);
    k_scan<<<1, 1024, 0, stream>>>(cntI, rowstart, chunkbase, MO);
    k_fill<<<(NF + 255) / 256, 256, 0, stream>>>(nxt, cur, rowstart, cursor, csr, NF);
    k_chunkfill<<<(CHUNK_CAP + 255) / 256, 256, 0, stream>>>(cntI, rowstart, chunkbase,
                                                             chv, choff, chlen, MO, CHUNK_CAP);

    // fused voxel-major big layer
    k_voxel<<<CHUNK_CAP / 4, 256, 0, stream>>>(outb, csr, chv, choff, chlen, P1, P2, b4, vsum);
    k_final<<<(MO * 128 + 255) / 256, 256, 0, stream>>>(vsum, cntI, b5, (float*)d_out, MO * 128);
}

// Round 7
// 428.418 us; speedup vs baseline: 2.9819x; 1.3867x over previous
//
#include <hip/hip_runtime.h>
#include <hip/hip_bf16.h>

#define NEG_SLOPE 0.1f
#define BN_EPS 1e-5f
#define MDV 25000
#define CHUNK_CAP 50016   // >= MO + NF/16 upper bound on total 16-row chunks

typedef __bf16 bf16_t;
typedef bf16_t bf16x8 __attribute__((ext_vector_type(8)));
typedef float f32x4 __attribute__((ext_vector_type(4)));

__device__ __forceinline__ float leaky(float x) { return x >= 0.0f ? x : NEG_SLOPE * x; }

// ---------------------------------------------------------------------------
// histogram both index arrays in one pass
__global__ void k_hist_both(const int* __restrict__ inv, int* __restrict__ cntD,
                            const int* __restrict__ nxt, int* __restrict__ cntI,
                            int N, int NF) {
    int f = blockIdx.x * 256 + threadIdx.x;
    if (f < N) atomicAdd(&cntD[inv[f]], 1);
    if (f < NF) atomicAdd(&cntI[nxt[f]], 1);
}

// ---------------------------------------------------------------------------
// grain scan: 2 blocks; block0 scans cntD->rowstartD, block1 scans cntI->rowstart(+chunkbase)
__global__ __launch_bounds__(1024) void k_scan_both(
        const int* __restrict__ cntD, int* __restrict__ rowstartD,
        const int* __restrict__ cntI, int* __restrict__ rowstart,
        int* __restrict__ chunkbase, int M) {
    const int* in; int* o1; int* o2;
    if (blockIdx.x == 0) { in = cntD; o1 = rowstartD; o2 = nullptr; }
    else                 { in = cntI; o1 = rowstart;  o2 = chunkbase; }
    int t = threadIdx.x;
    int T = (M + 1023) >> 10;
    int base = t * T;
    int s1 = 0, s2 = 0;
    for (int i = 0; i < T; i++) {
        int idx = base + i;
        int c = (idx < M) ? in[idx] : 0;
        s1 += c; s2 += (c + 15) >> 4;
    }
    __shared__ int sa[1024], sb[1024], sc[1024], sd[1024];
    sa[t] = s1; sc[t] = s2;
    __syncthreads();
    int *p = sa, *q = sb, *r = sc, *u = sd;
    for (int off = 1; off < 1024; off <<= 1) {
        int v1 = p[t] + ((t >= off) ? p[t - off] : 0);
        int v2 = r[t] + ((t >= off) ? r[t - off] : 0);
        q[t] = v1; u[t] = v2;
        __syncthreads();
        int* tmp = p; p = q; q = tmp;
        tmp = r; r = u; u = tmp;
    }
    int run1 = p[t] - s1;   // exclusive prefix
    int run2 = r[t] - s2;
    for (int i = 0; i < T; i++) {
        int idx = base + i;
        if (idx < M) {
            int c = in[idx];
            o1[idx] = run1; run1 += c;
            if (o2) { o2[idx] = run2; run2 += (c + 15) >> 4; }
        }
    }
    if (t == 1023) { o1[M] = run1; if (o2) o2[M] = run2; }
}

// ---------------------------------------------------------------------------
// fill both CSR lists; csrD holds point row f, csr holds gather row cur[f]
__global__ void k_fill_both(const int* __restrict__ inv, const int* __restrict__ rowstartD,
                            int* __restrict__ cursorD, int* __restrict__ csrD,
                            const int* __restrict__ nxt, const int* __restrict__ cur,
                            const int* __restrict__ rowstart, int* __restrict__ cursor,
                            int* __restrict__ csr, int N, int NF) {
    int f = blockIdx.x * 256 + threadIdx.x;
    if (f < N) {
        int v = inv[f];
        int pos = atomicAdd(&cursorD[v], 1);
        csrD[rowstartD[v] + pos] = f;
    }
    if (f < NF) {
        int v = nxt[f];
        int pos = atomicAdd(&cursor[v], 1);
        csr[rowstart[v] + pos] = cur[f];
    }
}

// build fixed 16-row chunk list; zero-len the tail beyond NC
__global__ void k_chunkfill(const int* __restrict__ cntI, const int* __restrict__ rowstart,
                            const int* __restrict__ chunkbase,
                            int* __restrict__ chv, int* __restrict__ choff, int* __restrict__ chlen,
                            int M, int cap) {
    int tid = blockIdx.x * 256 + threadIdx.x;
    int NC = chunkbase[M];
    if (tid < M) {
        int nf = cntI[tid];
        int nch = (nf + 15) >> 4;
        int cb = chunkbase[tid];
        int rs = rowstart[tid];
        for (int j = 0; j < nch; j++) {
            chv[cb + j] = tid;
            choff[cb + j] = rs + j * 16;
            chlen[cb + j] = min(16, nf - j * 16);
        }
    }
    if (tid >= NC && tid < cap) chlen[tid] = 0;
}

// ---------------------------------------------------------------------------
// voxel mean pooling via CSR gather (no atomics): one wave per voxel
__global__ __launch_bounds__(256) void k_downsum(
        const float* __restrict__ feat, const int* __restrict__ csrD,
        const int* __restrict__ rowstartD, const int* __restrict__ cntD,
        float* __restrict__ dsum, int MD) {
    int w = threadIdx.x >> 6, l = threadIdx.x & 63;
    int vox = blockIdx.x * 4 + w;
    if (vox >= MD) return;
    int cnt = cntD[vox];
    int start = rowstartD[vox];
    float s = 0.f;
    for (int p = 0; p < cnt; p++) {
        int row = csrD[start + p];
        s += feat[(size_t)row * 64 + l];
    }
    dsum[(size_t)vox * 64 + l] = s / fmaxf((float)cnt, 1.0f);
}

// ---------------------------------------------------------------------------
// grid-stride MLP64 + BN stats
__global__ __launch_bounds__(256) void k_mlp64(
        const float* __restrict__ in, const float* __restrict__ cnt,
        const float* __restrict__ W, const float* __restrict__ bias,
        float* __restrict__ out, float* __restrict__ ssum, float* __restrict__ ssq, int M) {
    __shared__ float a[4][64];
    int r = threadIdx.x >> 6;
    int c = threadIdx.x & 63;
    int ntiles = (M + 3) / 4;
    float ls = 0.0f, lq = 0.0f;
    for (int tile = blockIdx.x; tile < ntiles; tile += gridDim.x) {
        int row = tile * 4 + r;
        float v = 0.0f;
        if (row < M) {
            v = in[(size_t)row * 64 + c];
            if (cnt) v /= fmaxf(cnt[row], 1.0f);
        }
        __syncthreads();
        a[r][c] = v;
        __syncthreads();
        float acc = bias[c];
#pragma unroll
        for (int k = 0; k < 64; k++) acc = fmaf(a[r][k], W[k * 64 + c], acc);
        acc = leaky(acc);
        if (row < M) {
            out[(size_t)row * 64 + c] = acc;
            ls += acc;
            lq += acc * acc;
        }
    }
    __syncthreads();
    a[r][c] = ls;
    __syncthreads();
    if (r == 0) atomicAdd(&ssum[c], a[0][c] + a[1][c] + a[2][c] + a[3][c]);
    __syncthreads();
    a[r][c] = lq;
    __syncthreads();
    if (r == 0) atomicAdd(&ssq[c], a[0][c] + a[1][c] + a[2][c] + a[3][c]);
}

// ---------------------------------------------------------------------------
// fold BatchNorm into the next layer's weights
__global__ void k_fold(const float* __restrict__ ssum, const float* __restrict__ ssq,
                       const float* __restrict__ g, const float* __restrict__ be,
                       const float* __restrict__ W, const float* __restrict__ b,
                       float* __restrict__ Wp, float* __restrict__ bp, int M, int Cn) {
    int j = threadIdx.x;
    if (j >= Cn) return;
    float fM = (float)M;
    float accb = b[j];
    for (int k = 0; k < 64; k++) {
        float mu = ssum[k] / fM;
        float var = ssq[k] / fM - mu * mu;
        float rstd = rsqrtf(var + BN_EPS);
        float ak = g[k] * rstd;
        float ck = be[k] - mu * ak;
        float w = W[k * Cn + j];
        Wp[k * Cn + j] = ak * w;
        accb = fmaf(ck, w, accb);
    }
    bp[j] = accb;
}

// ---------------------------------------------------------------------------
// h3 (bf16) = leaky(in[M,64] @ W[64,128] + bias)
__global__ void k_mlp128(const float* __restrict__ in, const float* __restrict__ W,
                         const float* __restrict__ bias, bf16_t* __restrict__ out, int M) {
    __shared__ float a[2][64];
    int r = threadIdx.x >> 7;
    int c = threadIdx.x & 127;
    int row = blockIdx.x * 2 + r;
    if (c < 64) a[r][c] = (row < M) ? in[(size_t)row * 64 + c] : 0.0f;
    __syncthreads();
    if (row < M) {
        float acc = bias[c];
#pragma unroll
        for (int k = 0; k < 64; k++) acc = fmaf(a[r][k], W[k * 128 + c], acc);
        out[(size_t)row * 128 + c] = (bf16_t)leaky(acc);
    }
}

// ---------------------------------------------------------------------------
// Pack W4/W5/W_in into bf16 MFMA-B fragment order:
// P[((s*8+n)*64+l)*8+j] = W[(s*32+(l>>4)*8+j)][n*16+(l&15)]
__global__ void k_pack(const float* __restrict__ W4, const float* __restrict__ W5,
                       const float* __restrict__ Win,
                       bf16_t* __restrict__ P1, bf16_t* __restrict__ P2, bf16_t* __restrict__ P0) {
    int tid = blockIdx.x * 256 + threadIdx.x;
    const float* W; bf16_t* P; int t;
    if (tid < 4096)      { W = W4;  P = P1; t = tid; }
    else if (tid < 6144) { W = W5;  P = P2; t = tid - 4096; }
    else if (tid < 7168) { W = Win; P = P0; t = tid - 6144; }
    else return;
    int l = t & 63;
    int sn = t >> 6;
    int col = (sn & 7) * 16 + (l & 15);
    int k0 = (sn >> 3) * 32 + (l >> 4) * 8;
    bf16_t* dst = P + (size_t)t * 8;
#pragma unroll
    for (int j = 0; j < 8; j++) dst[j] = (bf16_t)W[(size_t)(k0 + j) * 128 + col];
}

// ---------------------------------------------------------------------------
// k_ident: MFMA identity branch + h3 concat.
// outb[row][0:128] = leaky(feat[row]@Win + bin); outb[row][128:256] = h3[inv[row]]
// block = 64 rows, 4 waves; wave w owns cols [w*32, w*32+32)
__global__ __launch_bounds__(256) void k_ident(
        const float* __restrict__ feat, const int* __restrict__ inv,
        const bf16_t* __restrict__ P0, const float* __restrict__ bin,
        const bf16_t* __restrict__ h3, bf16_t* __restrict__ outb, int N) {
    __shared__ bf16_t A[64 * 64];     // 8 KB
    __shared__ bf16_t C[64 * 128];    // 16 KB
    __shared__ int ividx[64];
    int tid = threadIdx.x;
    int base = blockIdx.x * 64;
    int valid = N - base; if (valid > 64) valid = 64;
    if (tid < 64) ividx[tid] = (tid < valid) ? inv[base + tid] : 0;

    // stage A: thread covers row=tid>>2, cols (tid&3)*16..+15; convert f32->bf16, swizzled
    {
        int r = tid >> 2, q = tid & 3;
        float4 v[4];
        if (r < valid) {
            const float4* src = reinterpret_cast<const float4*>(feat + (size_t)(base + r) * 64 + q * 16);
#pragma unroll
            for (int i = 0; i < 4; i++) v[i] = src[i];
        } else {
#pragma unroll
            for (int i = 0; i < 4; i++) v[i] = make_float4(0.f, 0.f, 0.f, 0.f);
        }
        bf16x8 h0, h1;
#pragma unroll
        for (int i = 0; i < 2; i++) {
            h0[i * 4 + 0] = (bf16_t)v[i].x; h0[i * 4 + 1] = (bf16_t)v[i].y;
            h0[i * 4 + 2] = (bf16_t)v[i].z; h0[i * 4 + 3] = (bf16_t)v[i].w;
            h1[i * 4 + 0] = (bf16_t)v[2 + i].x; h1[i * 4 + 1] = (bf16_t)v[2 + i].y;
            h1[i * 4 + 2] = (bf16_t)v[2 + i].z; h1[i * 4 + 3] = (bf16_t)v[2 + i].w;
        }
        int xa = (r & 7) << 3;
        *reinterpret_cast<bf16x8*>(&A[r * 64 + ((q * 16) ^ xa)]) = h0;
        *reinterpret_cast<bf16x8*>(&A[r * 64 + ((q * 16 + 8) ^ xa)]) = h1;
    }
    __syncthreads();

    int w = tid >> 6, l = tid & 63;
    int lg = l >> 4, lr = l & 15;
    int xr = (lr & 7) << 3;

    f32x4 acc[4][2];
#pragma unroll
    for (int t = 0; t < 2; t++) {
        float bv = bin[w * 32 + t * 16 + lr];
#pragma unroll
        for (int m = 0; m < 4; m++) acc[m][t] = (f32x4){bv, bv, bv, bv};
    }
#pragma unroll
    for (int s = 0; s < 2; s++) {
        bf16x8 a[4];
#pragma unroll
        for (int m = 0; m < 4; m++)
            a[m] = *reinterpret_cast<const bf16x8*>(&A[(m * 16 + lr) * 64 + (((s * 4 + lg) * 8) ^ xr)]);
#pragma unroll
        for (int t = 0; t < 2; t++) {
            bf16x8 b = *reinterpret_cast<const bf16x8*>(P0 + ((size_t)(s * 8 + w * 2 + t) * 64 + l) * 8);
#pragma unroll
            for (int m = 0; m < 4; m++)
                acc[m][t] = __builtin_amdgcn_mfma_f32_16x16x32_bf16(a[m], b, acc[m][t], 0, 0, 0);
        }
    }

    // C -> LDS (leaky, bf16, swizzled on element index)
#pragma unroll
    for (int m = 0; m < 4; m++)
#pragma unroll
        for (int t = 0; t < 2; t++)
#pragma unroll
            for (int rr = 0; rr < 4; rr++) {
                int row = m * 16 + lg * 4 + rr;
                int col = w * 32 + t * 16 + lr;
                C[row * 128 + (col ^ ((row & 7) << 3))] = (bf16_t)leaky(acc[m][t][rr]);
            }
    __syncthreads();

    // coalesced write-out: 1024 units = 64 rows x 16 chunks; each unit writes
    // one 16B C-chunk (identity half) AND one 16B h3-chunk (concat half)
#pragma unroll
    for (int i = 0; i < 4; i++) {
        int u = tid + i * 256;
        int row = u >> 4, seg = u & 15;
        if (row < valid) {
            bf16x8 val = *reinterpret_cast<const bf16x8*>(&C[row * 128 + ((seg * 8) ^ ((row & 7) << 3))]);
            *reinterpret_cast<bf16x8*>(&outb[(size_t)(base + row) * 256 + seg * 8]) = val;
            bf16x8 hv = *reinterpret_cast<const bf16x8*>(&h3[(size_t)ividx[row] * 128 + seg * 8]);
            *reinterpret_cast<bf16x8*>(&outb[(size_t)(base + row) * 256 + 128 + seg * 8]) = hv;
        }
    }
}

// ---------------------------------------------------------------------------
// k_voxel: block = 4 chunks (64 rows), 4 waves split the 128 output columns
__global__ __launch_bounds__(256) void k_voxel(
        const bf16_t* __restrict__ outb, const int* __restrict__ csr,
        const int* __restrict__ chv, const int* __restrict__ choff, const int* __restrict__ chlen,
        const bf16_t* __restrict__ P1, const bf16_t* __restrict__ P2,
        const float* __restrict__ b4, float* __restrict__ vsum) {
    __shared__ bf16_t Atile[64 * 256];   // 32KB; Mid[64*128] aliases the first 16KB
    bf16_t* Mid = Atile;
    __shared__ int ridx[64];
    __shared__ int mv[4], mlen[4];
    __shared__ int moff[4];

    int tid = threadIdx.x;
    int basec = blockIdx.x * 4;
    if (tid < 4) {
        mv[tid] = chv[basec + tid];
        moff[tid] = choff[basec + tid];
        mlen[tid] = chlen[basec + tid];
    }
    __syncthreads();
    if (mlen[0] + mlen[1] + mlen[2] + mlen[3] == 0) return;   // uniform exit

    int w = tid >> 6, l = tid & 63;
    int lg = l >> 4, lr = l & 15;
    int xr = (lr & 7) << 3;

    // preload GEMM1 B fragments (this wave's quarter) - overlaps gather staging
    bf16x8 b1r[8][2];
#pragma unroll
    for (int s = 0; s < 8; s++)
#pragma unroll
        for (int t = 0; t < 2; t++)
            b1r[s][t] = *reinterpret_cast<const bf16x8*>(P1 + ((size_t)(s * 8 + w * 2 + t) * 64 + l) * 8);

    if (tid < 64) {
        int m = tid >> 4, r = tid & 15;
        ridx[tid] = (r < mlen[m]) ? csr[moff[m] + r] : -1;
    }
    __syncthreads();

    // gather 64 rows x 512B: 4 threads/row, 8 float4 each
    {
        int row = tid >> 2;
        int cid = ridx[row];
        int xa = (row & 7) << 3;
#pragma unroll
        for (int j = 0; j < 8; j++) {
            int q = (tid & 3) + 4 * j;
            float4 val = make_float4(0.f, 0.f, 0.f, 0.f);
            if (cid >= 0) val = reinterpret_cast<const float4*>(outb + (size_t)cid * 256)[q];
            *reinterpret_cast<float4*>(&Atile[row * 256 + ((q * 8) ^ xa)]) = val;
        }
    }
    __syncthreads();

    // GEMM1: K=256 (8 k-steps), per wave 2 n-tiles, 4 m-tiles
    f32x4 acc1[4][2];
#pragma unroll
    for (int t = 0; t < 2; t++) {
        float bv = b4[w * 32 + t * 16 + lr];
#pragma unroll
        for (int m = 0; m < 4; m++) acc1[m][t] = (f32x4){bv, bv, bv, bv};
    }
#pragma unroll
    for (int s = 0; s < 8; s++) {
        bf16x8 a[4];
#pragma unroll
        for (int m = 0; m < 4; m++)
            a[m] = *reinterpret_cast<const bf16x8*>(&Atile[(m * 16 + lr) * 256 + (((s * 4 + lg) * 8) ^ xr)]);
#pragma unroll
        for (int t = 0; t < 2; t++)
#pragma unroll
            for (int m = 0; m < 4; m++)
                acc1[m][t] = __builtin_amdgcn_mfma_f32_16x16x32_bf16(a[m], b1r[s][t], acc1[m][t], 0, 0, 0);
    }
    __syncthreads();   // all GEMM1 Atile reads complete before Mid overwrites

    // Mid = leaky(acc1) bf16, swizzled
#pragma unroll
    for (int m = 0; m < 4; m++)
#pragma unroll
        for (int t = 0; t < 2; t++)
#pragma unroll
            for (int rr = 0; rr < 4; rr++) {
                int row = m * 16 + lg * 4 + rr;
                int col = w * 32 + t * 16 + lr;
                Mid[row * 128 + (col ^ ((row & 7) << 3))] = (bf16_t)leaky(acc1[m][t][rr]);
            }
    __syncthreads();

    // GEMM2: K=128 (4 k-steps)
    f32x4 acc2[4][2];
#pragma unroll
    for (int t = 0; t < 2; t++)
#pragma unroll
        for (int m = 0; m < 4; m++) acc2[m][t] = (f32x4){0.f, 0.f, 0.f, 0.f};
#pragma unroll
    for (int s = 0; s < 4; s++) {
        bf16x8 a[4];
#pragma unroll
        for (int m = 0; m < 4; m++)
            a[m] = *reinterpret_cast<const bf16x8*>(&Mid[(m * 16 + lr) * 128 + ((s * 32 + lg * 8) ^ xr)]);
#pragma unroll
        for (int t = 0; t < 2; t++) {
            bf16x8 b = *reinterpret_cast<const bf16x8*>(P2 + ((size_t)(s * 8 + w * 2 + t) * 64 + l) * 8);
#pragma unroll
            for (int m = 0; m < 4; m++)
                acc2[m][t] = __builtin_amdgcn_mfma_f32_16x16x32_bf16(a[m], b, acc2[m][t], 0, 0, 0);
        }
    }

    // masked row-sum per chunk, butterfly over lg, one atomic per (chunk, 16 lanes)
#pragma unroll
    for (int m = 0; m < 4; m++) {
        int len = mlen[m];
        if (len == 0) continue;   // uniform across block
#pragma unroll
        for (int t = 0; t < 2; t++) {
            float s = 0.0f;
#pragma unroll
            for (int rr = 0; rr < 4; rr++) {
                int r = lg * 4 + rr;
                if (r < len) s += acc2[m][t][rr];
            }
            s += __shfl_xor(s, 16);
            s += __shfl_xor(s, 32);
            if (lg == 0) atomicAdd(&vsum[(size_t)mv[m] * 128 + w * 32 + t * 16 + lr], s);
        }
    }
}

// ---------------------------------------------------------------------------
// final: out = vsum/cnt + b5 (0 where cnt==0)
__global__ void k_final(const float* __restrict__ vsum, const int* __restrict__ cntI,
                        const float* __restrict__ b5, float* __restrict__ out, int total) {
    int i = blockIdx.x * blockDim.x + threadIdx.x;
    if (i < total) {
        int m = i >> 7;
        int nf = cntI[m];
        out[i] = (nf > 0) ? (vsum[i] / (float)nf + b5[i & 127]) : 0.0f;
    }
}

// ---------------------------------------------------------------------------
extern "C" void kernel_launch(void* const* d_in, const int* in_sizes, int n_in,
                              void* d_out, int out_size, void* d_ws, size_t ws_size,
                              hipStream_t stream) {
    const float* feat = (const float*)d_in[0];
    const int*   inv  = (const int*)d_in[1];
    const int*   cur  = (const int*)d_in[2];
    const int*   nxt  = (const int*)d_in[3];
    const float* W_in = (const float*)d_in[6];
    const float* b_in = (const float*)d_in[7];
    const float* W1   = (const float*)d_in[8];
    const float* b1   = (const float*)d_in[9];
    const float* g1   = (const float*)d_in[10];
    const float* be1  = (const float*)d_in[11];
    const float* W2   = (const float*)d_in[12];
    const float* b2   = (const float*)d_in[13];
    const float* g2   = (const float*)d_in[14];
    const float* be2  = (const float*)d_in[15];
    const float* W3   = (const float*)d_in[16];
    const float* b3   = (const float*)d_in[17];
    const float* W4   = (const float*)d_in[18];
    const float* b4   = (const float*)d_in[19];
    const float* W5   = (const float*)d_in[20];
    const float* b5   = (const float*)d_in[21];

    const int N  = in_sizes[0] / 64;
    const int NF = in_sizes[2];
    const int MO = out_size / 128;
    const int MD = MDV;   // n_down (device scalar; fixed problem size)

    float* ws = (float*)d_ws;
    size_t off = 0;
    // ---- zeroed region ----
    float* vsum  = ws + off; off += (size_t)MO * 128;
    float* ssum1 = ws + off; off += 64;
    float* ssq1  = ws + off; off += 64;
    float* ssum2 = ws + off; off += 64;
    float* ssq2  = ws + off; off += 64;
    int* cntD    = (int*)(ws + off); off += (size_t)MD;
    int* cursorD = (int*)(ws + off); off += (size_t)MD;
    int* cntI    = (int*)(ws + off); off += (size_t)MO;
    int* cursor  = (int*)(ws + off); off += (size_t)MO;
    size_t zeroElems = off;
    // ---- non-zeroed ----
    float* dsum = ws + off; off += (size_t)MD * 64;
    float* t1   = ws + off; off += (size_t)MD * 64;
    float* t2   = ws + off; off += (size_t)MD * 64;
    float* Wp2  = ws + off; off += 64 * 64;
    float* bp2  = ws + off; off += 64;
    float* Wp3  = ws + off; off += 64 * 128;
    float* bp3  = ws + off; off += 128;
    int* rowstartD = (int*)(ws + off); off += (size_t)MD + 1;
    int* rowstart  = (int*)(ws + off); off += (size_t)MO + 1;
    int* chunkbase = (int*)(ws + off); off += (size_t)MO + 1;
    int* csrD      = (int*)(ws + off); off += (size_t)N;
    int* csr       = (int*)(ws + off); off += (size_t)NF;
    int* chv       = (int*)(ws + off); off += CHUNK_CAP;
    int* choff     = (int*)(ws + off); off += CHUNK_CAP;
    int* chlen     = (int*)(ws + off); off += CHUNK_CAP;
    bf16_t* bws = (bf16_t*)(ws + off);
    size_t boff = 0;
    bf16_t* h3b  = bws + boff; boff += (size_t)MD * 128;
    bf16_t* outb = bws + boff; boff += (size_t)N * 256;
    bf16_t* P0   = bws + boff; boff += 8192;
    bf16_t* P1   = bws + boff; boff += 32768;
    bf16_t* P2   = bws + boff; boff += 16384;
    (void)ws_size; (void)n_in;

    hipMemsetAsync(d_ws, 0, zeroElems * sizeof(float), stream);

    int gmax = (NF > N ? NF : N);
    k_hist_both<<<(gmax + 255) / 256, 256, 0, stream>>>(inv, cntD, nxt, cntI, N, NF);
    k_scan_both<<<2, 1024, 0, stream>>>(cntD, rowstartD, cntI, rowstart, chunkbase, MD);
    k_fill_both<<<(gmax + 255) / 256, 256, 0, stream>>>(inv, rowstartD, cursorD, csrD,
                                                        nxt, cur, rowstart, cursor, csr, N, NF);
    k_chunkfill<<<(CHUNK_CAP + 255) / 256, 256, 0, stream>>>(cntI, rowstart, chunkbase,
                                                             chv, choff, chlen, MO, CHUNK_CAP);

    // front MLP path
    k_downsum<<<(MD + 3) / 4, 256, 0, stream>>>(feat, csrD, rowstartD, cntD, dsum, MD);
    k_mlp64<<<512, 256, 0, stream>>>(dsum, nullptr, W1, b1, t1, ssum1, ssq1, MD);
    k_fold<<<1, 64, 0, stream>>>(ssum1, ssq1, g1, be1, W2, b2, Wp2, bp2, MD, 64);
    k_mlp64<<<512, 256, 0, stream>>>(t1, nullptr, Wp2, bp2, t2, ssum2, ssq2, MD);
    k_fold<<<1, 128, 0, stream>>>(ssum2, ssq2, g2, be2, W3, b3, Wp3, bp3, MD, 128);
    k_mlp128<<<(MD + 1) / 2, 256, 0, stream>>>(t2, Wp3, bp3, h3b, MD);
    k_pack<<<28, 256, 0, stream>>>(W4, W5, W_in, P1, P2, P0);
    k_ident<<<(N + 63) / 64, 256, 0, stream>>>(feat, inv, P0, b_in, h3b, outb, N);

    // fused voxel-major big layer
    k_voxel<<<CHUNK_CAP / 4, 256, 0, stream>>>(outb, csr, chv, choff, chlen, P1, P2, b4, vsum);
    k_final<<<(MO * 128 + 255) / 256, 256, 0, stream>>>(vsum, cntI, b5, (float*)d_out, MO * 128);
}

// Round 8
// 312.641 us; speedup vs baseline: 4.0861x; 1.3703x over previous
//
#include <hip/hip_runtime.h>
#include <hip/hip_bf16.h>

#define NEG_SLOPE 0.1f
#define BN_EPS 1e-5f
#define MDV 25000

typedef __bf16 bf16_t;
typedef bf16_t bf16x8 __attribute__((ext_vector_type(8)));
typedef bf16_t bf16x2 __attribute__((ext_vector_type(2)));
typedef float f32x4 __attribute__((ext_vector_type(4)));

__device__ __forceinline__ float leaky(float x) { return x >= 0.0f ? x : NEG_SLOPE * x; }

// ---------------------------------------------------------------------------
// histogram both index arrays in one pass
__global__ void k_hist_both(const int* __restrict__ inv, int* __restrict__ cntD,
                            const int* __restrict__ nxt, int* __restrict__ cntI,
                            int N, int NF) {
    int f = blockIdx.x * 256 + threadIdx.x;
    if (f < N) atomicAdd(&cntD[inv[f]], 1);
    if (f < NF) atomicAdd(&cntI[nxt[f]], 1);
}

// ---------------------------------------------------------------------------
// grain scan: block0 scans cntD[MD]->rowstartD, block1 scans cntI[MO]->rowstart
__global__ __launch_bounds__(1024) void k_scan_both(
        const int* __restrict__ cntD, int* __restrict__ rowstartD, int MD,
        const int* __restrict__ cntI, int* __restrict__ rowstart, int MO) {
    const int* in; int* o1; int M;
    if (blockIdx.x == 0) { in = cntD; o1 = rowstartD; M = MD; }
    else                 { in = cntI; o1 = rowstart;  M = MO; }
    int t = threadIdx.x;
    int T = (M + 1023) >> 10;
    int base = t * T;
    int s1 = 0;
    for (int i = 0; i < T; i++) {
        int idx = base + i;
        s1 += (idx < M) ? in[idx] : 0;
    }
    __shared__ int sa[1024], sb[1024];
    sa[t] = s1;
    __syncthreads();
    int *p = sa, *q = sb;
    for (int off = 1; off < 1024; off <<= 1) {
        int v1 = p[t] + ((t >= off) ? p[t - off] : 0);
        q[t] = v1;
        __syncthreads();
        int* tmp = p; p = q; q = tmp;
    }
    int run1 = p[t] - s1;   // exclusive prefix of this thread's grain
    for (int i = 0; i < T; i++) {
        int idx = base + i;
        if (idx < M) {
            o1[idx] = run1;
            run1 += in[idx];
        }
    }
    if (t == 1023) o1[M] = run1;
}

// ---------------------------------------------------------------------------
// fill both CSR lists; csrA holds cur[f], csrB holds inv[cur[f]], csrD holds f
__global__ void k_fill_both(const int* __restrict__ inv, const int* __restrict__ rowstartD,
                            int* __restrict__ cursorD, int* __restrict__ csrD,
                            const int* __restrict__ nxt, const int* __restrict__ cur,
                            const int* __restrict__ rowstart, int* __restrict__ cursor,
                            int* __restrict__ csrA, int* __restrict__ csrB,
                            int N, int NF) {
    int f = blockIdx.x * 256 + threadIdx.x;
    if (f < N) {
        int v = inv[f];
        int pos = atomicAdd(&cursorD[v], 1);
        csrD[rowstartD[v] + pos] = f;
    }
    if (f < NF) {
        int v = nxt[f];
        int pos = atomicAdd(&cursor[v], 1);
        int c = cur[f];
        csrA[rowstart[v] + pos] = c;
        csrB[rowstart[v] + pos] = inv[c];
    }
}

// ---------------------------------------------------------------------------
// voxel mean pooling via CSR gather (no atomics): one wave per voxel
__global__ __launch_bounds__(256) void k_downsum(
        const float* __restrict__ feat, const int* __restrict__ csrD,
        const int* __restrict__ rowstartD, const int* __restrict__ cntD,
        float* __restrict__ dsum, int MD) {
    int w = threadIdx.x >> 6, l = threadIdx.x & 63;
    int vox = blockIdx.x * 4 + w;
    if (vox >= MD) return;
    int cnt = cntD[vox];
    int start = rowstartD[vox];
    float s = 0.f;
    for (int p = 0; p < cnt; p++) {
        int row = csrD[start + p];
        s += feat[(size_t)row * 64 + l];
    }
    dsum[(size_t)vox * 64 + l] = s / fmaxf((float)cnt, 1.0f);
}

// ---------------------------------------------------------------------------
// grid-stride MLP64 + BN stats
__global__ __launch_bounds__(256) void k_mlp64(
        const float* __restrict__ in, const float* __restrict__ cnt,
        const float* __restrict__ W, const float* __restrict__ bias,
        float* __restrict__ out, float* __restrict__ ssum, float* __restrict__ ssq, int M) {
    __shared__ float a[4][64];
    int r = threadIdx.x >> 6;
    int c = threadIdx.x & 63;
    int ntiles = (M + 3) / 4;
    float ls = 0.0f, lq = 0.0f;
    for (int tile = blockIdx.x; tile < ntiles; tile += gridDim.x) {
        int row = tile * 4 + r;
        float v = 0.0f;
        if (row < M) {
            v = in[(size_t)row * 64 + c];
            if (cnt) v /= fmaxf(cnt[row], 1.0f);
        }
        __syncthreads();
        a[r][c] = v;
        __syncthreads();
        float acc = bias[c];
#pragma unroll
        for (int k = 0; k < 64; k++) acc = fmaf(a[r][k], W[k * 64 + c], acc);
        acc = leaky(acc);
        if (row < M) {
            out[(size_t)row * 64 + c] = acc;
            ls += acc;
            lq += acc * acc;
        }
    }
    __syncthreads();
    a[r][c] = ls;
    __syncthreads();
    if (r == 0) atomicAdd(&ssum[c], a[0][c] + a[1][c] + a[2][c] + a[3][c]);
    __syncthreads();
    a[r][c] = lq;
    __syncthreads();
    if (r == 0) atomicAdd(&ssq[c], a[0][c] + a[1][c] + a[2][c] + a[3][c]);
}

// ---------------------------------------------------------------------------
// fold BatchNorm into the next layer's weights (f32 output, for VALU k_mlp64)
__global__ void k_fold(const float* __restrict__ ssum, const float* __restrict__ ssq,
                       const float* __restrict__ g, const float* __restrict__ be,
                       const float* __restrict__ W, const float* __restrict__ b,
                       float* __restrict__ Wp, float* __restrict__ bp, int M, int Cn) {
    int j = threadIdx.x;
    if (j >= Cn) return;
    float fM = (float)M;
    float accb = b[j];
    for (int k = 0; k < 64; k++) {
        float mu = ssum[k] / fM;
        float var = ssq[k] / fM - mu * mu;
        float rstd = rsqrtf(var + BN_EPS);
        float ak = g[k] * rstd;
        float ck = be[k] - mu * ak;
        float w = W[k * Cn + j];
        Wp[k * Cn + j] = ak * w;
        accb = fmaf(ck, w, accb);
    }
    bp[j] = accb;
}

// ---------------------------------------------------------------------------
// fold BN2 into W3 [64x128], writing bf16 MFMA-B packed fragments directly
// pack rule: for (k,col): s=k>>5, n=col>>4, l=((k>>3)&3)*16+(col&15), jj=k&7
__global__ void k_fold_packed(const float* __restrict__ ssum, const float* __restrict__ ssq,
                              const float* __restrict__ g, const float* __restrict__ be,
                              const float* __restrict__ W, const float* __restrict__ b,
                              bf16_t* __restrict__ P, float* __restrict__ bp, int M) {
    int j = threadIdx.x;   // 0..127 output column
    if (j >= 128) return;
    float fM = (float)M;
    float accb = b[j];
    int n = j >> 4, jr = j & 15;
    for (int k = 0; k < 64; k++) {
        float mu = ssum[k] / fM;
        float var = ssq[k] / fM - mu * mu;
        float rstd = rsqrtf(var + BN_EPS);
        float ak = g[k] * rstd;
        float ck = be[k] - mu * ak;
        float w = W[k * 128 + j];
        accb = fmaf(ck, w, accb);
        int s = k >> 5, l = ((k >> 3) & 3) * 16 + jr, jj = k & 7;
        P[((size_t)((s * 8 + n) * 64 + l)) * 8 + jj] = (bf16_t)(ak * w);
    }
    bp[j] = accb;
}

// ---------------------------------------------------------------------------
// Pack W4/W5/W_in into bf16 MFMA-B fragment order:
// P[((s*8+n)*64+l)*8+j] = W[(s*32+(l>>4)*8+j)][n*16+(l&15)]
__global__ void k_pack(const float* __restrict__ W4, const float* __restrict__ W5,
                       const float* __restrict__ Win,
                       bf16_t* __restrict__ P1, bf16_t* __restrict__ P2, bf16_t* __restrict__ P0) {
    int tid = blockIdx.x * 256 + threadIdx.x;
    const float* W; bf16_t* P; int t;
    if (tid < 4096)      { W = W4;  P = P1; t = tid; }
    else if (tid < 6144) { W = W5;  P = P2; t = tid - 4096; }
    else if (tid < 7168) { W = Win; P = P0; t = tid - 6144; }
    else return;
    int l = t & 63;
    int sn = t >> 6;
    int col = (sn & 7) * 16 + (l & 15);
    int k0 = (sn >> 3) * 32 + (l >> 4) * 8;
    bf16_t* dst = P + (size_t)t * 8;
#pragma unroll
    for (int j = 0; j < 8; j++) dst[j] = (bf16_t)W[(size_t)(k0 + j) * 128 + col];
}

// ---------------------------------------------------------------------------
// k_two_gemm: out[M,128] = leaky(in[M,64] @ Pa + ba) @ Pb (+ bb)   (bf16 out)
// block = 64 rows, 4 waves; wave w owns cols [w*32, w*32+32) of both GEMMs
__global__ __launch_bounds__(256) void k_two_gemm(
        const float* __restrict__ in, const bf16_t* __restrict__ Pa,
        const float* __restrict__ ba, const bf16_t* __restrict__ Pb,
        const float* __restrict__ bb, bf16_t* __restrict__ out, int M) {
    __shared__ bf16_t A[64 * 64];     // 8 KB
    __shared__ bf16_t C[64 * 128];    // 16 KB
    int tid = threadIdx.x;
    int base = blockIdx.x * 64;
    int valid = M - base; if (valid > 64) valid = 64;

    {   // stage A: thread covers row=tid>>2, 16 cols, f32->bf16, swizzled
        int r = tid >> 2, q = tid & 3;
        float4 v[4];
        if (r < valid) {
            const float4* src = reinterpret_cast<const float4*>(in + (size_t)(base + r) * 64 + q * 16);
#pragma unroll
            for (int i = 0; i < 4; i++) v[i] = src[i];
        } else {
#pragma unroll
            for (int i = 0; i < 4; i++) v[i] = make_float4(0.f, 0.f, 0.f, 0.f);
        }
        bf16x8 h0, h1;
#pragma unroll
        for (int i = 0; i < 2; i++) {
            h0[i * 4 + 0] = (bf16_t)v[i].x; h0[i * 4 + 1] = (bf16_t)v[i].y;
            h0[i * 4 + 2] = (bf16_t)v[i].z; h0[i * 4 + 3] = (bf16_t)v[i].w;
            h1[i * 4 + 0] = (bf16_t)v[2 + i].x; h1[i * 4 + 1] = (bf16_t)v[2 + i].y;
            h1[i * 4 + 2] = (bf16_t)v[2 + i].z; h1[i * 4 + 3] = (bf16_t)v[2 + i].w;
        }
        int xa = (r & 7) << 3;
        *reinterpret_cast<bf16x8*>(&A[r * 64 + ((q * 16) ^ xa)]) = h0;
        *reinterpret_cast<bf16x8*>(&A[r * 64 + ((q * 16 + 8) ^ xa)]) = h1;
    }
    __syncthreads();

    int w = tid >> 6, l = tid & 63;
    int lg = l >> 4, lr = l & 15;
    int xr = (lr & 7) << 3;

    // GEMM a: K=64 (2 k-steps), acc init ba, leaky -> C
    f32x4 acc[4][2];
#pragma unroll
    for (int t = 0; t < 2; t++) {
        float bv = ba[w * 32 + t * 16 + lr];
#pragma unroll
        for (int m = 0; m < 4; m++) acc[m][t] = (f32x4){bv, bv, bv, bv};
    }
#pragma unroll
    for (int s = 0; s < 2; s++) {
        bf16x8 a[4];
#pragma unroll
        for (int m = 0; m < 4; m++)
            a[m] = *reinterpret_cast<const bf16x8*>(&A[(m * 16 + lr) * 64 + (((s * 4 + lg) * 8) ^ xr)]);
#pragma unroll
        for (int t = 0; t < 2; t++) {
            bf16x8 b = *reinterpret_cast<const bf16x8*>(Pa + ((size_t)(s * 8 + w * 2 + t) * 64 + l) * 8);
#pragma unroll
            for (int m = 0; m < 4; m++)
                acc[m][t] = __builtin_amdgcn_mfma_f32_16x16x32_bf16(a[m], b, acc[m][t], 0, 0, 0);
        }
    }
#pragma unroll
    for (int m = 0; m < 4; m++)
#pragma unroll
        for (int t = 0; t < 2; t++)
#pragma unroll
            for (int rr = 0; rr < 4; rr++) {
                int row = m * 16 + lg * 4 + rr;
                int col = w * 32 + t * 16 + lr;
                C[row * 128 + (col ^ ((row & 7) << 3))] = (bf16_t)leaky(acc[m][t][rr]);
            }
    __syncthreads();

    // GEMM b: K=128 (4 k-steps), acc init bb (or 0)
    f32x4 acc2[4][2];
#pragma unroll
    for (int t = 0; t < 2; t++) {
        float bv = bb ? bb[w * 32 + t * 16 + lr] : 0.0f;
#pragma unroll
        for (int m = 0; m < 4; m++) acc2[m][t] = (f32x4){bv, bv, bv, bv};
    }
#pragma unroll
    for (int s = 0; s < 4; s++) {
        bf16x8 a[4];
#pragma unroll
        for (int m = 0; m < 4; m++)
            a[m] = *reinterpret_cast<const bf16x8*>(&C[(m * 16 + lr) * 128 + ((s * 32 + lg * 8) ^ xr)]);
#pragma unroll
        for (int t = 0; t < 2; t++) {
            bf16x8 b = *reinterpret_cast<const bf16x8*>(Pb + ((size_t)(s * 8 + w * 2 + t) * 64 + l) * 8);
#pragma unroll
            for (int m = 0; m < 4; m++)
                acc2[m][t] = __builtin_amdgcn_mfma_f32_16x16x32_bf16(a[m], b, acc2[m][t], 0, 0, 0);
        }
    }
    __syncthreads();   // all C reads complete before overwrite

    // overwrite C with acc2 (no activation), then coalesced 16B write-out
#pragma unroll
    for (int m = 0; m < 4; m++)
#pragma unroll
        for (int t = 0; t < 2; t++)
#pragma unroll
            for (int rr = 0; rr < 4; rr++) {
                int row = m * 16 + lg * 4 + rr;
                int col = w * 32 + t * 16 + lr;
                C[row * 128 + (col ^ ((row & 7) << 3))] = (bf16_t)acc2[m][t][rr];
            }
    __syncthreads();
#pragma unroll
    for (int i = 0; i < 4; i++) {
        int u = tid + i * 256;
        int row = u >> 4, seg = u & 15;
        if (row < valid) {
            bf16x8 val = *reinterpret_cast<const bf16x8*>(&C[row * 128 + ((seg * 8) ^ ((row & 7) << 3))]);
            *reinterpret_cast<bf16x8*>(&out[(size_t)(base + row) * 128 + seg * 8]) = val;
        }
    }
}

// ---------------------------------------------------------------------------
// k_gather_mean: one wave per output voxel.
// meanB[v] = mean over points f in voxel v of leaky(z1[cur[f]] + z2[inv[cur[f]]])
// (b4 is folded into z1). No atomics, no LDS, no barriers.
__global__ __launch_bounds__(256) void k_gather_mean(
        const bf16_t* __restrict__ z1, const bf16_t* __restrict__ z2,
        const int* __restrict__ csrA, const int* __restrict__ csrB,
        const int* __restrict__ rowstart, const int* __restrict__ cntI,
        bf16_t* __restrict__ meanB, int MO) {
    int w = threadIdx.x >> 6, l = threadIdx.x & 63;
    int v = blockIdx.x * 4 + w;
    if (v >= MO) return;
    int cnt = cntI[v];
    int start = rowstart[v];
    float s0 = 0.f, s1 = 0.f;
    for (int p = 0; p < cnt; p++) {
        int ia = csrA[start + p];
        int ib = csrB[start + p];
        bf16x2 za = *reinterpret_cast<const bf16x2*>(&z1[(size_t)ia * 128 + l * 2]);
        bf16x2 zb = *reinterpret_cast<const bf16x2*>(&z2[(size_t)ib * 128 + l * 2]);
        s0 += leaky((float)za[0] + (float)zb[0]);
        s1 += leaky((float)za[1] + (float)zb[1]);
    }
    float sc = (cnt > 0) ? (1.0f / (float)cnt) : 0.0f;
    bf16x2 mv;
    mv[0] = (bf16_t)(s0 * sc);
    mv[1] = (bf16_t)(s1 * sc);
    *reinterpret_cast<bf16x2*>(&meanB[(size_t)v * 128 + l * 2]) = mv;
}

// ---------------------------------------------------------------------------
// k_vox2: out[MO,128] f32 = meanB[MO,128] @ P2 + b5, masked to 0 where cnt==0
// A-fragments read straight from global (meanB is L2-resident, 6.4 MB)
__global__ __launch_bounds__(256) void k_vox2(
        const bf16_t* __restrict__ meanB, const int* __restrict__ cntI,
        const bf16_t* __restrict__ P2, const float* __restrict__ b5,
        float* __restrict__ outp, int MO) {
    int tid = threadIdx.x;
    int base = blockIdx.x * 64;
    int w = tid >> 6, l = tid & 63;
    int lg = l >> 4, lr = l & 15;
    f32x4 acc[4][2];
#pragma unroll
    for (int t = 0; t < 2; t++) {
        float bv = b5[w * 32 + t * 16 + lr];
#pragma unroll
        for (int m = 0; m < 4; m++) acc[m][t] = (f32x4){bv, bv, bv, bv};
    }
#pragma unroll
    for (int s = 0; s < 4; s++) {
        bf16x8 a[4];
#pragma unroll
        for (int m = 0; m < 4; m++) {
            int row = base + m * 16 + lr;
            a[m] = *reinterpret_cast<const bf16x8*>(&meanB[(size_t)row * 128 + (s * 4 + lg) * 8]);
        }
#pragma unroll
        for (int t = 0; t < 2; t++) {
            bf16x8 b = *reinterpret_cast<const bf16x8*>(P2 + ((size_t)(s * 8 + w * 2 + t) * 64 + l) * 8);
#pragma unroll
            for (int m = 0; m < 4; m++)
                acc[m][t] = __builtin_amdgcn_mfma_f32_16x16x32_bf16(a[m], b, acc[m][t], 0, 0, 0);
        }
    }
#pragma unroll
    for (int m = 0; m < 4; m++)
#pragma unroll
        for (int t = 0; t < 2; t++)
#pragma unroll
            for (int rr = 0; rr < 4; rr++) {
                int row = base + m * 16 + lg * 4 + rr;
                if (row < MO) {
                    float val = (cntI[row] > 0) ? acc[m][t][rr] : 0.0f;
                    outp[(size_t)row * 128 + w * 32 + t * 16 + lr] = val;
                }
            }
}

// ---------------------------------------------------------------------------
extern "C" void kernel_launch(void* const* d_in, const int* in_sizes, int n_in,
                              void* d_out, int out_size, void* d_ws, size_t ws_size,
                              hipStream_t stream) {
    const float* feat = (const float*)d_in[0];
    const int*   inv  = (const int*)d_in[1];
    const int*   cur  = (const int*)d_in[2];
    const int*   nxt  = (const int*)d_in[3];
    const float* W_in = (const float*)d_in[6];
    const float* b_in = (const float*)d_in[7];
    const float* W1   = (const float*)d_in[8];
    const float* b1   = (const float*)d_in[9];
    const float* g1   = (const float*)d_in[10];
    const float* be1  = (const float*)d_in[11];
    const float* W2   = (const float*)d_in[12];
    const float* b2   = (const float*)d_in[13];
    const float* g2   = (const float*)d_in[14];
    const float* be2  = (const float*)d_in[15];
    const float* W3   = (const float*)d_in[16];
    const float* b3   = (const float*)d_in[17];
    const float* W4   = (const float*)d_in[18];
    const float* b4   = (const float*)d_in[19];
    const float* W5   = (const float*)d_in[20];
    const float* b5   = (const float*)d_in[21];

    const int N  = in_sizes[0] / 64;
    const int NF = in_sizes[2];
    const int MO = out_size / 128;
    const int MD = MDV;   // n_down (device scalar; fixed problem size)

    float* ws = (float*)d_ws;
    size_t off = 0;
    // ---- zeroed region (stats + counters only) ----
    float* ssum1 = ws + off; off += 64;
    float* ssq1  = ws + off; off += 64;
    float* ssum2 = ws + off; off += 64;
    float* ssq2  = ws + off; off += 64;
    int* cntD    = (int*)(ws + off); off += (size_t)MD;
    int* cursorD = (int*)(ws + off); off += (size_t)MD;
    int* cntI    = (int*)(ws + off); off += (size_t)MO;
    int* cursor  = (int*)(ws + off); off += (size_t)MO;
    size_t zeroElems = off;
    // ---- non-zeroed ----
    float* dsum = ws + off; off += (size_t)MD * 64;
    float* t1   = ws + off; off += (size_t)MD * 64;
    float* t2   = ws + off; off += (size_t)MD * 64;
    float* Wp2  = ws + off; off += 64 * 64;
    float* bp2  = ws + off; off += 64;
    float* bp3  = ws + off; off += 128;
    int* rowstartD = (int*)(ws + off); off += (size_t)MD + 1;
    int* rowstart  = (int*)(ws + off); off += (size_t)MO + 1;
    int* csrD      = (int*)(ws + off); off += (size_t)N;
    int* csrA      = (int*)(ws + off); off += (size_t)NF;
    int* csrB      = (int*)(ws + off); off += (size_t)NF;
    bf16_t* bws = (bf16_t*)(ws + off);
    size_t boff = 0;
    bf16_t* z1    = bws + boff; boff += (size_t)N * 128;
    bf16_t* z2    = bws + boff; boff += (size_t)MD * 128;
    bf16_t* meanB = bws + boff; boff += (size_t)MO * 128 + 4096;  // +slack for tail OOB reads
    bf16_t* P0    = bws + boff; boff += 8192;
    bf16_t* P1    = bws + boff; boff += 32768;
    bf16_t* P2    = bws + boff; boff += 16384;
    bf16_t* P3    = bws + boff; boff += 8192;
    (void)ws_size; (void)n_in;

    hipMemsetAsync(d_ws, 0, zeroElems * sizeof(float), stream);

    int gmax = (NF > N ? NF : N);
    k_hist_both<<<(gmax + 255) / 256, 256, 0, stream>>>(inv, cntD, nxt, cntI, N, NF);
    k_scan_both<<<2, 1024, 0, stream>>>(cntD, rowstartD, MD, cntI, rowstart, MO);
    k_fill_both<<<(gmax + 255) / 256, 256, 0, stream>>>(inv, rowstartD, cursorD, csrD,
                                                        nxt, cur, rowstart, cursor,
                                                        csrA, csrB, N, NF);

    // front MLP path (voxel-pooled features -> h3 -> z2)
    k_downsum<<<(MD + 3) / 4, 256, 0, stream>>>(feat, csrD, rowstartD, cntD, dsum, MD);
    k_mlp64<<<512, 256, 0, stream>>>(dsum, nullptr, W1, b1, t1, ssum1, ssq1, MD);
    k_fold<<<1, 64, 0, stream>>>(ssum1, ssq1, g1, be1, W2, b2, Wp2, bp2, MD, 64);
    k_mlp64<<<512, 256, 0, stream>>>(t1, nullptr, Wp2, bp2, t2, ssum2, ssq2, MD);
    k_fold_packed<<<1, 128, 0, stream>>>(ssum2, ssq2, g2, be2, W3, b3, P3, bp3, MD);
    k_pack<<<28, 256, 0, stream>>>(W4, W5, W_in, P1, P2, P0);

    // z2 = leaky(t2 @ Wp3 + bp3) @ W4_bot          [MD x 128], L2-resident
    k_two_gemm<<<(MD + 63) / 64, 256, 0, stream>>>(t2, P3, bp3, P1 + 16384, nullptr, z2, MD);
    // z1 = leaky(feat @ Win + bin) @ W4_top + b4   [N x 128]
    k_two_gemm<<<(N + 63) / 64, 256, 0, stream>>>(feat, P0, b_in, P1, b4, z1, N);

    // per-voxel gather-mean of leaky(z1+z2)  (the former hot kernel, now GEMM-free)
    k_gather_mean<<<(MO + 3) / 4, 256, 0, stream>>>(z1, z2, csrA, csrB, rowstart, cntI, meanB, MO);
    // out = meanB @ W5 + b5 (masked where empty)
    k_vox2<<<(MO + 63) / 64, 256, 0, stream>>>(meanB, cntI, P2, b5, (float*)d_out, MO);
}

// Round 9
// 308.526 us; speedup vs baseline: 4.1406x; 1.0133x over previous
//
#include <hip/hip_runtime.h>
#include <hip/hip_bf16.h>

#define NEG_SLOPE 0.1f
#define BN_EPS 1e-5f
#define MDV 25000

typedef __bf16 bf16_t;
typedef bf16_t bf16x8 __attribute__((ext_vector_type(8)));
typedef bf16_t bf16x4 __attribute__((ext_vector_type(4)));
typedef float f32x4 __attribute__((ext_vector_type(4)));

__device__ __forceinline__ float leaky(float x) { return x >= 0.0f ? x : NEG_SLOPE * x; }

// ---------------------------------------------------------------------------
// histogram both index arrays in one pass
__global__ void k_hist_both(const int* __restrict__ inv, int* __restrict__ cntD,
                            const int* __restrict__ nxt, int* __restrict__ cntI,
                            int N, int NF) {
    int f = blockIdx.x * 256 + threadIdx.x;
    if (f < N) atomicAdd(&cntD[inv[f]], 1);
    if (f < NF) atomicAdd(&cntI[nxt[f]], 1);
}

// ---------------------------------------------------------------------------
// grain scan: block0 scans cntD[MD]->rowstartD, block1 scans cntI[MO]->rowstart
__global__ __launch_bounds__(1024) void k_scan_both(
        const int* __restrict__ cntD, int* __restrict__ rowstartD, int MD,
        const int* __restrict__ cntI, int* __restrict__ rowstart, int MO) {
    const int* in; int* o1; int M;
    if (blockIdx.x == 0) { in = cntD; o1 = rowstartD; M = MD; }
    else                 { in = cntI; o1 = rowstart;  M = MO; }
    int t = threadIdx.x;
    int T = (M + 1023) >> 10;
    int base = t * T;
    int s1 = 0;
    for (int i = 0; i < T; i++) {
        int idx = base + i;
        s1 += (idx < M) ? in[idx] : 0;
    }
    __shared__ int sa[1024], sb[1024];
    sa[t] = s1;
    __syncthreads();
    int *p = sa, *q = sb;
    for (int off = 1; off < 1024; off <<= 1) {
        int v1 = p[t] + ((t >= off) ? p[t - off] : 0);
        q[t] = v1;
        __syncthreads();
        int* tmp = p; p = q; q = tmp;
    }
    int run1 = p[t] - s1;   // exclusive prefix of this thread's grain
    for (int i = 0; i < T; i++) {
        int idx = base + i;
        if (idx < M) {
            o1[idx] = run1;
            run1 += in[idx];
        }
    }
    if (t == 1023) o1[M] = run1;
}

// ---------------------------------------------------------------------------
// fill both CSR lists; csrD holds f; csrAB holds (cur[f], inv[cur[f]]) packed
__global__ void k_fill_both(const int* __restrict__ inv, const int* __restrict__ rowstartD,
                            int* __restrict__ cursorD, int* __restrict__ csrD,
                            const int* __restrict__ nxt, const int* __restrict__ cur,
                            const int* __restrict__ rowstart, int* __restrict__ cursor,
                            int2* __restrict__ csrAB, int N, int NF) {
    int f = blockIdx.x * 256 + threadIdx.x;
    if (f < N) {
        int v = inv[f];
        int pos = atomicAdd(&cursorD[v], 1);
        csrD[rowstartD[v] + pos] = f;
    }
    if (f < NF) {
        int v = nxt[f];
        int pos = atomicAdd(&cursor[v], 1);
        int c = cur[f];
        csrAB[rowstart[v] + pos] = make_int2(c, inv[c]);
    }
}

// ---------------------------------------------------------------------------
// fused voxel mean-pool + MLP64 + BN stats. One wave per voxel (grid-stride
// tiles of 4). Wave-private LDS row -> no in-loop barriers.
__global__ __launch_bounds__(256) void k_pool_mlp64(
        const float* __restrict__ feat, const int* __restrict__ csrD,
        const int* __restrict__ rowstartD, const int* __restrict__ cntD,
        const float* __restrict__ W, const float* __restrict__ bias,
        float* __restrict__ out, float* __restrict__ ssum, float* __restrict__ ssq, int MD) {
    __shared__ float a[4][64];
    int w = threadIdx.x >> 6, l = threadIdx.x & 63;
    float ls = 0.0f, lq = 0.0f;
    int ntiles = (MD + 3) >> 2;
    for (int tile = blockIdx.x; tile < ntiles; tile += gridDim.x) {
        int vox = tile * 4 + w;
        float s = 0.0f; int cnt = 0;
        if (vox < MD) {
            cnt = cntD[vox];
            int start = rowstartD[vox];
            for (int p = 0; p < cnt; p++)
                s += feat[(size_t)csrD[start + p] * 64 + l];
        }
        a[w][l] = (cnt > 0) ? s / (float)cnt : 0.0f;
        float acc = bias[l];
#pragma unroll
        for (int k = 0; k < 64; k++) acc = fmaf(a[w][k], W[k * 64 + l], acc);
        acc = leaky(acc);
        if (vox < MD) {
            out[(size_t)vox * 64 + l] = acc;
            ls += acc;
            lq += acc * acc;
        }
    }
    __syncthreads();
    a[w][l] = ls;
    __syncthreads();
    if (w == 0) atomicAdd(&ssum[l], a[0][l] + a[1][l] + a[2][l] + a[3][l]);
    __syncthreads();
    a[w][l] = lq;
    __syncthreads();
    if (w == 0) atomicAdd(&ssq[l], a[0][l] + a[1][l] + a[2][l] + a[3][l]);
}

// ---------------------------------------------------------------------------
// grid-stride MLP64 + BN stats (dense input)
__global__ __launch_bounds__(256) void k_mlp64(
        const float* __restrict__ in, const float* __restrict__ W,
        const float* __restrict__ bias, float* __restrict__ out,
        float* __restrict__ ssum, float* __restrict__ ssq, int M) {
    __shared__ float a[4][64];
    int r = threadIdx.x >> 6;
    int c = threadIdx.x & 63;
    int ntiles = (M + 3) / 4;
    float ls = 0.0f, lq = 0.0f;
    for (int tile = blockIdx.x; tile < ntiles; tile += gridDim.x) {
        int row = tile * 4 + r;
        float v = (row < M) ? in[(size_t)row * 64 + c] : 0.0f;
        __syncthreads();
        a[r][c] = v;
        __syncthreads();
        float acc = bias[c];
#pragma unroll
        for (int k = 0; k < 64; k++) acc = fmaf(a[r][k], W[k * 64 + c], acc);
        acc = leaky(acc);
        if (row < M) {
            out[(size_t)row * 64 + c] = acc;
            ls += acc;
            lq += acc * acc;
        }
    }
    __syncthreads();
    a[r][c] = ls;
    __syncthreads();
    if (r == 0) atomicAdd(&ssum[c], a[0][c] + a[1][c] + a[2][c] + a[3][c]);
    __syncthreads();
    a[r][c] = lq;
    __syncthreads();
    if (r == 0) atomicAdd(&ssq[c], a[0][c] + a[1][c] + a[2][c] + a[3][c]);
}

// ---------------------------------------------------------------------------
// fold BatchNorm into the next layer's weights (f32 output)
__global__ void k_fold(const float* __restrict__ ssum, const float* __restrict__ ssq,
                       const float* __restrict__ g, const float* __restrict__ be,
                       const float* __restrict__ W, const float* __restrict__ b,
                       float* __restrict__ Wp, float* __restrict__ bp, int M, int Cn) {
    int j = threadIdx.x;
    if (j >= Cn) return;
    float fM = (float)M;
    float accb = b[j];
    for (int k = 0; k < 64; k++) {
        float mu = ssum[k] / fM;
        float var = ssq[k] / fM - mu * mu;
        float rstd = rsqrtf(var + BN_EPS);
        float ak = g[k] * rstd;
        float ck = be[k] - mu * ak;
        float w = W[k * Cn + j];
        Wp[k * Cn + j] = ak * w;
        accb = fmaf(ck, w, accb);
    }
    bp[j] = accb;
}

// ---------------------------------------------------------------------------
// fold BN2 into W3 [64x128], writing bf16 MFMA-B packed fragments directly
__global__ void k_fold_packed(const float* __restrict__ ssum, const float* __restrict__ ssq,
                              const float* __restrict__ g, const float* __restrict__ be,
                              const float* __restrict__ W, const float* __restrict__ b,
                              bf16_t* __restrict__ P, float* __restrict__ bp, int M) {
    int j = threadIdx.x;   // 0..127 output column
    if (j >= 128) return;
    float fM = (float)M;
    float accb = b[j];
    int n = j >> 4, jr = j & 15;
    for (int k = 0; k < 64; k++) {
        float mu = ssum[k] / fM;
        float var = ssq[k] / fM - mu * mu;
        float rstd = rsqrtf(var + BN_EPS);
        float ak = g[k] * rstd;
        float ck = be[k] - mu * ak;
        float w = W[k * 128 + j];
        accb = fmaf(ck, w, accb);
        int s = k >> 5, l = ((k >> 3) & 3) * 16 + jr, jj = k & 7;
        P[((size_t)((s * 8 + n) * 64 + l)) * 8 + jj] = (bf16_t)(ak * w);
    }
    bp[j] = accb;
}

// ---------------------------------------------------------------------------
// Pack W4/W5/W_in into bf16 MFMA-B fragment order
__global__ void k_pack(const float* __restrict__ W4, const float* __restrict__ W5,
                       const float* __restrict__ Win,
                       bf16_t* __restrict__ P1, bf16_t* __restrict__ P2, bf16_t* __restrict__ P0) {
    int tid = blockIdx.x * 256 + threadIdx.x;
    const float* W; bf16_t* P; int t;
    if (tid < 4096)      { W = W4;  P = P1; t = tid; }
    else if (tid < 6144) { W = W5;  P = P2; t = tid - 4096; }
    else if (tid < 7168) { W = Win; P = P0; t = tid - 6144; }
    else return;
    int l = t & 63;
    int sn = t >> 6;
    int col = (sn & 7) * 16 + (l & 15);
    int k0 = (sn >> 3) * 32 + (l >> 4) * 8;
    bf16_t* dst = P + (size_t)t * 8;
#pragma unroll
    for (int j = 0; j < 8; j++) dst[j] = (bf16_t)W[(size_t)(k0 + j) * 128 + col];
}

// ---------------------------------------------------------------------------
// k_two_gemm: out[M,128] = leaky(in[M,64] @ Pa + ba) @ Pb (+ bb)   (bf16 out)
__global__ __launch_bounds__(256) void k_two_gemm(
        const float* __restrict__ in, const bf16_t* __restrict__ Pa,
        const float* __restrict__ ba, const bf16_t* __restrict__ Pb,
        const float* __restrict__ bb, bf16_t* __restrict__ out, int M) {
    __shared__ bf16_t A[64 * 64];     // 8 KB
    __shared__ bf16_t C[64 * 128];    // 16 KB
    int tid = threadIdx.x;
    int base = blockIdx.x * 64;
    int valid = M - base; if (valid > 64) valid = 64;

    {   // stage A: thread covers row=tid>>2, 16 cols, f32->bf16, swizzled
        int r = tid >> 2, q = tid & 3;
        float4 v[4];
        if (r < valid) {
            const float4* src = reinterpret_cast<const float4*>(in + (size_t)(base + r) * 64 + q * 16);
#pragma unroll
            for (int i = 0; i < 4; i++) v[i] = src[i];
        } else {
#pragma unroll
            for (int i = 0; i < 4; i++) v[i] = make_float4(0.f, 0.f, 0.f, 0.f);
        }
        bf16x8 h0, h1;
#pragma unroll
        for (int i = 0; i < 2; i++) {
            h0[i * 4 + 0] = (bf16_t)v[i].x; h0[i * 4 + 1] = (bf16_t)v[i].y;
            h0[i * 4 + 2] = (bf16_t)v[i].z; h0[i * 4 + 3] = (bf16_t)v[i].w;
            h1[i * 4 + 0] = (bf16_t)v[2 + i].x; h1[i * 4 + 1] = (bf16_t)v[2 + i].y;
            h1[i * 4 + 2] = (bf16_t)v[2 + i].z; h1[i * 4 + 3] = (bf16_t)v[2 + i].w;
        }
        int xa = (r & 7) << 3;
        *reinterpret_cast<bf16x8*>(&A[r * 64 + ((q * 16) ^ xa)]) = h0;
        *reinterpret_cast<bf16x8*>(&A[r * 64 + ((q * 16 + 8) ^ xa)]) = h1;
    }
    __syncthreads();

    int w = tid >> 6, l = tid & 63;
    int lg = l >> 4, lr = l & 15;
    int xr = (lr & 7) << 3;

    // GEMM a: K=64 (2 k-steps), acc init ba, leaky -> C
    f32x4 acc[4][2];
#pragma unroll
    for (int t = 0; t < 2; t++) {
        float bv = ba[w * 32 + t * 16 + lr];
#pragma unroll
        for (int m = 0; m < 4; m++) acc[m][t] = (f32x4){bv, bv, bv, bv};
    }
#pragma unroll
    for (int s = 0; s < 2; s++) {
        bf16x8 a[4];
#pragma unroll
        for (int m = 0; m < 4; m++)
            a[m] = *reinterpret_cast<const bf16x8*>(&A[(m * 16 + lr) * 64 + (((s * 4 + lg) * 8) ^ xr)]);
#pragma unroll
        for (int t = 0; t < 2; t++) {
            bf16x8 b = *reinterpret_cast<const bf16x8*>(Pa + ((size_t)(s * 8 + w * 2 + t) * 64 + l) * 8);
#pragma unroll
            for (int m = 0; m < 4; m++)
                acc[m][t] = __builtin_amdgcn_mfma_f32_16x16x32_bf16(a[m], b, acc[m][t], 0, 0, 0);
        }
    }
#pragma unroll
    for (int m = 0; m < 4; m++)
#pragma unroll
        for (int t = 0; t < 2; t++)
#pragma unroll
            for (int rr = 0; rr < 4; rr++) {
                int row = m * 16 + lg * 4 + rr;
                int col = w * 32 + t * 16 + lr;
                C[row * 128 + (col ^ ((row & 7) << 3))] = (bf16_t)leaky(acc[m][t][rr]);
            }
    __syncthreads();

    // GEMM b: K=128 (4 k-steps), acc init bb (or 0)
    f32x4 acc2[4][2];
#pragma unroll
    for (int t = 0; t < 2; t++) {
        float bv = bb ? bb[w * 32 + t * 16 + lr] : 0.0f;
#pragma unroll
        for (int m = 0; m < 4; m++) acc2[m][t] = (f32x4){bv, bv, bv, bv};
    }
#pragma unroll
    for (int s = 0; s < 4; s++) {
        bf16x8 a[4];
#pragma unroll
        for (int m = 0; m < 4; m++)
            a[m] = *reinterpret_cast<const bf16x8*>(&C[(m * 16 + lr) * 128 + ((s * 32 + lg * 8) ^ xr)]);
#pragma unroll
        for (int t = 0; t < 2; t++) {
            bf16x8 b = *reinterpret_cast<const bf16x8*>(Pb + ((size_t)(s * 8 + w * 2 + t) * 64 + l) * 8);
#pragma unroll
            for (int m = 0; m < 4; m++)
                acc2[m][t] = __builtin_amdgcn_mfma_f32_16x16x32_bf16(a[m], b, acc2[m][t], 0, 0, 0);
        }
    }
    __syncthreads();   // all C reads complete before overwrite

    // overwrite C with acc2 (no activation), then coalesced 16B write-out
#pragma unroll
    for (int m = 0; m < 4; m++)
#pragma unroll
        for (int t = 0; t < 2; t++)
#pragma unroll
            for (int rr = 0; rr < 4; rr++) {
                int row = m * 16 + lg * 4 + rr;
                int col = w * 32 + t * 16 + lr;
                C[row * 128 + (col ^ ((row & 7) << 3))] = (bf16_t)acc2[m][t][rr];
            }
    __syncthreads();
#pragma unroll
    for (int i = 0; i < 4; i++) {
        int u = tid + i * 256;
        int row = u >> 4, seg = u & 15;
        if (row < valid) {
            bf16x8 val = *reinterpret_cast<const bf16x8*>(&C[row * 128 + ((seg * 8) ^ ((row & 7) << 3))]);
            *reinterpret_cast<bf16x8*>(&out[(size_t)(base + row) * 128 + seg * 8]) = val;
        }
    }
}

// ---------------------------------------------------------------------------
// k_gather_mean v2: one wave per output voxel; 2 points per instruction
// (lanes 0-31 cover point p, lanes 32-63 point p+1; bf16x4 per lane), x2 unroll.
// meanB[v] = mean_f leaky(z1[cur[f]] + z2[inv[cur[f]]])
__global__ __launch_bounds__(256) void k_gather_mean(
        const bf16_t* __restrict__ z1, const bf16_t* __restrict__ z2,
        const int2* __restrict__ csrAB, const int* __restrict__ rowstart,
        const int* __restrict__ cntI, bf16_t* __restrict__ meanB, int MO) {
    int w = threadIdx.x >> 6, l = threadIdx.x & 63;
    int half = l >> 5, sub = l & 31;
    int v = blockIdx.x * 4 + w;
    if (v >= MO) return;
    int cnt = cntI[v];
    int start = rowstart[v];
    float s[4] = {0.f, 0.f, 0.f, 0.f};
    int p = 0;
    for (; p + 4 <= cnt; p += 4) {
        int2 ea = csrAB[start + p + half];
        int2 eb = csrAB[start + p + 2 + half];
        bf16x4 za0 = *reinterpret_cast<const bf16x4*>(&z1[(size_t)ea.x * 128 + sub * 4]);
        bf16x4 zb0 = *reinterpret_cast<const bf16x4*>(&z2[(size_t)ea.y * 128 + sub * 4]);
        bf16x4 za1 = *reinterpret_cast<const bf16x4*>(&z1[(size_t)eb.x * 128 + sub * 4]);
        bf16x4 zb1 = *reinterpret_cast<const bf16x4*>(&z2[(size_t)eb.y * 128 + sub * 4]);
#pragma unroll
        for (int j = 0; j < 4; j++) {
            s[j] += leaky((float)za0[j] + (float)zb0[j]);
            s[j] += leaky((float)za1[j] + (float)zb1[j]);
        }
    }
    for (; p + 2 <= cnt; p += 2) {
        int2 e = csrAB[start + p + half];
        bf16x4 za = *reinterpret_cast<const bf16x4*>(&z1[(size_t)e.x * 128 + sub * 4]);
        bf16x4 zb = *reinterpret_cast<const bf16x4*>(&z2[(size_t)e.y * 128 + sub * 4]);
#pragma unroll
        for (int j = 0; j < 4; j++) s[j] += leaky((float)za[j] + (float)zb[j]);
    }
    if (p < cnt && half == 0) {
        int2 e = csrAB[start + p];
        bf16x4 za = *reinterpret_cast<const bf16x4*>(&z1[(size_t)e.x * 128 + sub * 4]);
        bf16x4 zb = *reinterpret_cast<const bf16x4*>(&z2[(size_t)e.y * 128 + sub * 4]);
#pragma unroll
        for (int j = 0; j < 4; j++) s[j] += leaky((float)za[j] + (float)zb[j]);
    }
    float sc = (cnt > 0) ? (1.0f / (float)cnt) : 0.0f;
    bf16x4 mv;
#pragma unroll
    for (int j = 0; j < 4; j++) {
        s[j] += __shfl_xor(s[j], 32);
        mv[j] = (bf16_t)(s[j] * sc);
    }
    if (half == 0)
        *reinterpret_cast<bf16x4*>(&meanB[(size_t)v * 128 + sub * 4]) = mv;
}

// ---------------------------------------------------------------------------
// k_vox2: out[MO,128] f32 = meanB[MO,128] @ P2 + b5, masked to 0 where cnt==0
__global__ __launch_bounds__(256) void k_vox2(
        const bf16_t* __restrict__ meanB, const int* __restrict__ cntI,
        const bf16_t* __restrict__ P2, const float* __restrict__ b5,
        float* __restrict__ outp, int MO) {
    int tid = threadIdx.x;
    int base = blockIdx.x * 64;
    int w = tid >> 6, l = tid & 63;
    int lg = l >> 4, lr = l & 15;
    f32x4 acc[4][2];
#pragma unroll
    for (int t = 0; t < 2; t++) {
        float bv = b5[w * 32 + t * 16 + lr];
#pragma unroll
        for (int m = 0; m < 4; m++) acc[m][t] = (f32x4){bv, bv, bv, bv};
    }
#pragma unroll
    for (int s = 0; s < 4; s++) {
        bf16x8 a[4];
#pragma unroll
        for (int m = 0; m < 4; m++) {
            int row = base + m * 16 + lr;
            a[m] = *reinterpret_cast<const bf16x8*>(&meanB[(size_t)row * 128 + (s * 4 + lg) * 8]);
        }
#pragma unroll
        for (int t = 0; t < 2; t++) {
            bf16x8 b = *reinterpret_cast<const bf16x8*>(P2 + ((size_t)(s * 8 + w * 2 + t) * 64 + l) * 8);
#pragma unroll
            for (int m = 0; m < 4; m++)
                acc[m][t] = __builtin_amdgcn_mfma_f32_16x16x32_bf16(a[m], b, acc[m][t], 0, 0, 0);
        }
    }
#pragma unroll
    for (int m = 0; m < 4; m++)
#pragma unroll
        for (int t = 0; t < 2; t++)
#pragma unroll
            for (int rr = 0; rr < 4; rr++) {
                int row = base + m * 16 + lg * 4 + rr;
                if (row < MO) {
                    float val = (cntI[row] > 0) ? acc[m][t][rr] : 0.0f;
                    outp[(size_t)row * 128 + w * 32 + t * 16 + lr] = val;
                }
            }
}

// ---------------------------------------------------------------------------
extern "C" void kernel_launch(void* const* d_in, const int* in_sizes, int n_in,
                              void* d_out, int out_size, void* d_ws, size_t ws_size,
                              hipStream_t stream) {
    const float* feat = (const float*)d_in[0];
    const int*   inv  = (const int*)d_in[1];
    const int*   cur  = (const int*)d_in[2];
    const int*   nxt  = (const int*)d_in[3];
    const float* W_in = (const float*)d_in[6];
    const float* b_in = (const float*)d_in[7];
    const float* W1   = (const float*)d_in[8];
    const float* b1   = (const float*)d_in[9];
    const float* g1   = (const float*)d_in[10];
    const float* be1  = (const float*)d_in[11];
    const float* W2   = (const float*)d_in[12];
    const float* b2   = (const float*)d_in[13];
    const float* g2   = (const float*)d_in[14];
    const float* be2  = (const float*)d_in[15];
    const float* W3   = (const float*)d_in[16];
    const float* b3   = (const float*)d_in[17];
    const float* W4   = (const float*)d_in[18];
    const float* b4   = (const float*)d_in[19];
    const float* W5   = (const float*)d_in[20];
    const float* b5   = (const float*)d_in[21];

    const int N  = in_sizes[0] / 64;
    const int NF = in_sizes[2];
    const int MO = out_size / 128;
    const int MD = MDV;   // n_down (device scalar; fixed problem size)

    float* ws = (float*)d_ws;
    size_t off = 0;
    // ---- zeroed region (stats + counters only) ----
    float* ssum1 = ws + off; off += 64;
    float* ssq1  = ws + off; off += 64;
    float* ssum2 = ws + off; off += 64;
    float* ssq2  = ws + off; off += 64;
    int* cntD    = (int*)(ws + off); off += (size_t)MD;
    int* cursorD = (int*)(ws + off); off += (size_t)MD;
    int* cntI    = (int*)(ws + off); off += (size_t)MO;
    int* cursor  = (int*)(ws + off); off += (size_t)MO;
    size_t zeroElems = off;
    // ---- non-zeroed ----
    float* t1   = ws + off; off += (size_t)MD * 64;
    float* t2   = ws + off; off += (size_t)MD * 64;
    float* Wp2  = ws + off; off += 64 * 64;
    float* bp2  = ws + off; off += 64;
    float* bp3  = ws + off; off += 128;
    int* rowstartD = (int*)(ws + off); off += (size_t)MD + 1;
    int* rowstart  = (int*)(ws + off); off += (size_t)MO + 1;
    int* csrD      = (int*)(ws + off); off += (size_t)N;
    off = (off + 1) & ~(size_t)1;   // 8B align for int2
    int2* csrAB    = (int2*)(ws + off); off += (size_t)NF * 2;
    bf16_t* bws = (bf16_t*)(ws + off);
    size_t boff = 0;
    bf16_t* z1    = bws + boff; boff += (size_t)N * 128;
    bf16_t* z2    = bws + boff; boff += (size_t)MD * 128;
    bf16_t* meanB = bws + boff; boff += (size_t)MO * 128 + 4096;  // +slack for tail OOB reads
    bf16_t* P0    = bws + boff; boff += 8192;
    bf16_t* P1    = bws + boff; boff += 32768;
    bf16_t* P2    = bws + boff; boff += 16384;
    bf16_t* P3    = bws + boff; boff += 8192;
    (void)ws_size; (void)n_in;

    hipMemsetAsync(d_ws, 0, zeroElems * sizeof(float), stream);

    int gmax = (NF > N ? NF : N);
    k_hist_both<<<(gmax + 255) / 256, 256, 0, stream>>>(inv, cntD, nxt, cntI, N, NF);
    k_scan_both<<<2, 1024, 0, stream>>>(cntD, rowstartD, MD, cntI, rowstart, MO);
    k_fill_both<<<(gmax + 255) / 256, 256, 0, stream>>>(inv, rowstartD, cursorD, csrD,
                                                        nxt, cur, rowstart, cursor,
                                                        csrAB, N, NF);

    // front MLP path (fused pool+MLP1 -> BN-fold -> MLP2 -> packed fold)
    k_pool_mlp64<<<512, 256, 0, stream>>>(feat, csrD, rowstartD, cntD, W1, b1, t1, ssum1, ssq1, MD);
    k_fold<<<1, 64, 0, stream>>>(ssum1, ssq1, g1, be1, W2, b2, Wp2, bp2, MD, 64);
    k_mlp64<<<512, 256, 0, stream>>>(t1, Wp2, bp2, t2, ssum2, ssq2, MD);
    k_fold_packed<<<1, 128, 0, stream>>>(ssum2, ssq2, g2, be2, W3, b3, P3, bp3, MD);
    k_pack<<<28, 256, 0, stream>>>(W4, W5, W_in, P1, P2, P0);

    // z2 = leaky(t2 @ Wp3 + bp3) @ W4_bot          [MD x 128], L2-resident
    k_two_gemm<<<(MD + 63) / 64, 256, 0, stream>>>(t2, P3, bp3, P1 + 16384, nullptr, z2, MD);
    // z1 = leaky(feat @ Win + bin) @ W4_top + b4   [N x 128]
    k_two_gemm<<<(N + 63) / 64, 256, 0, stream>>>(feat, P0, b_in, P1, b4, z1, N);

    // per-voxel paired gather-mean of leaky(z1+z2)
    k_gather_mean<<<(MO + 3) / 4, 256, 0, stream>>>(z1, z2, csrAB, rowstart, cntI, meanB, MO);
    // out = meanB @ W5 + b5 (masked where empty)
    k_vox2<<<(MO + 63) / 64, 256, 0, stream>>>(meanB, cntI, P2, b5, (float*)d_out, MO);
}

// Round 10
// 288.032 us; speedup vs baseline: 4.4352x; 1.0711x over previous
//
#include <hip/hip_runtime.h>
#include <hip/hip_bf16.h>

#define NEG_SLOPE 0.1f
#define BN_EPS 1e-5f
#define MDV 25000

typedef __bf16 bf16_t;
typedef bf16_t bf16x8 __attribute__((ext_vector_type(8)));
typedef bf16_t bf16x4 __attribute__((ext_vector_type(4)));
typedef float f32x4 __attribute__((ext_vector_type(4)));

__device__ __forceinline__ float leaky(float x) { return x >= 0.0f ? x : NEG_SLOPE * x; }

// ---------------------------------------------------------------------------
// histogram both index arrays in one pass
__global__ void k_hist_both(const int* __restrict__ inv, int* __restrict__ cntD,
                            const int* __restrict__ nxt, int* __restrict__ cntI,
                            int N, int NF) {
    int f = blockIdx.x * 256 + threadIdx.x;
    if (f < N) atomicAdd(&cntD[inv[f]], 1);
    if (f < NF) atomicAdd(&cntI[nxt[f]], 1);
}

// ---------------------------------------------------------------------------
// grain scan: block0 scans cntD[MD]->rowstartD, block1 scans cntI[MO]->rowstart
__global__ __launch_bounds__(1024) void k_scan_both(
        const int* __restrict__ cntD, int* __restrict__ rowstartD, int MD,
        const int* __restrict__ cntI, int* __restrict__ rowstart, int MO) {
    const int* in; int* o1; int M;
    if (blockIdx.x == 0) { in = cntD; o1 = rowstartD; M = MD; }
    else                 { in = cntI; o1 = rowstart;  M = MO; }
    int t = threadIdx.x;
    int T = (M + 1023) >> 10;
    int base = t * T;
    int s1 = 0;
    for (int i = 0; i < T; i++) {
        int idx = base + i;
        s1 += (idx < M) ? in[idx] : 0;
    }
    __shared__ int sa[1024], sb[1024];
    sa[t] = s1;
    __syncthreads();
    int *p = sa, *q = sb;
    for (int off = 1; off < 1024; off <<= 1) {
        int v1 = p[t] + ((t >= off) ? p[t - off] : 0);
        q[t] = v1;
        __syncthreads();
        int* tmp = p; p = q; q = tmp;
    }
    int run1 = p[t] - s1;   // exclusive prefix of this thread's grain
    for (int i = 0; i < T; i++) {
        int idx = base + i;
        if (idx < M) {
            o1[idx] = run1;
            run1 += in[idx];
        }
    }
    if (t == 1023) o1[M] = run1;
}

// ---------------------------------------------------------------------------
// fill both CSR lists; csrD holds f; csrAB holds (cur[f], inv[cur[f]]) packed
__global__ void k_fill_both(const int* __restrict__ inv, const int* __restrict__ rowstartD,
                            int* __restrict__ cursorD, int* __restrict__ csrD,
                            const int* __restrict__ nxt, const int* __restrict__ cur,
                            const int* __restrict__ rowstart, int* __restrict__ cursor,
                            int2* __restrict__ csrAB, int N, int NF) {
    int f = blockIdx.x * 256 + threadIdx.x;
    if (f < N) {
        int v = inv[f];
        int pos = atomicAdd(&cursorD[v], 1);
        csrD[rowstartD[v] + pos] = f;
    }
    if (f < NF) {
        int v = nxt[f];
        int pos = atomicAdd(&cursor[v], 1);
        int c = cur[f];
        csrAB[rowstart[v] + pos] = make_int2(c, inv[c]);
    }
}

// ---------------------------------------------------------------------------
// voxel mean pooling via CSR gather: one wave per voxel, x2 unrolled loads
__global__ __launch_bounds__(256) void k_downsum(
        const float* __restrict__ feat, const int* __restrict__ csrD,
        const int* __restrict__ rowstartD, const int* __restrict__ cntD,
        float* __restrict__ dsum, int MD) {
    int w = threadIdx.x >> 6, l = threadIdx.x & 63;
    int vox = blockIdx.x * 4 + w;
    if (vox >= MD) return;
    int cnt = cntD[vox];
    int start = rowstartD[vox];
    float s = 0.f;
    int p = 0;
    for (; p + 2 <= cnt; p += 2) {
        int r0 = csrD[start + p];
        int r1 = csrD[start + p + 1];
        s += feat[(size_t)r0 * 64 + l] + feat[(size_t)r1 * 64 + l];
    }
    if (p < cnt) s += feat[(size_t)csrD[start + p] * 64 + l];
    dsum[(size_t)vox * 64 + l] = s / fmaxf((float)cnt, 1.0f);
}

// ---------------------------------------------------------------------------
// grid-stride MLP64 + BN stats (dense input)
__global__ __launch_bounds__(256) void k_mlp64(
        const float* __restrict__ in, const float* __restrict__ W,
        const float* __restrict__ bias, float* __restrict__ out,
        float* __restrict__ ssum, float* __restrict__ ssq, int M) {
    __shared__ float a[4][64];
    int r = threadIdx.x >> 6;
    int c = threadIdx.x & 63;
    int ntiles = (M + 3) / 4;
    float ls = 0.0f, lq = 0.0f;
    for (int tile = blockIdx.x; tile < ntiles; tile += gridDim.x) {
        int row = tile * 4 + r;
        float v = (row < M) ? in[(size_t)row * 64 + c] : 0.0f;
        __syncthreads();
        a[r][c] = v;
        __syncthreads();
        float acc = bias[c];
#pragma unroll
        for (int k = 0; k < 64; k++) acc = fmaf(a[r][k], W[k * 64 + c], acc);
        acc = leaky(acc);
        if (row < M) {
            out[(size_t)row * 64 + c] = acc;
            ls += acc;
            lq += acc * acc;
        }
    }
    __syncthreads();
    a[r][c] = ls;
    __syncthreads();
    if (r == 0) atomicAdd(&ssum[c], a[0][c] + a[1][c] + a[2][c] + a[3][c]);
    __syncthreads();
    a[r][c] = lq;
    __syncthreads();
    if (r == 0) atomicAdd(&ssq[c], a[0][c] + a[1][c] + a[2][c] + a[3][c]);
}

// ---------------------------------------------------------------------------
// fold BatchNorm into the next layer's weights (f32 output)
__global__ void k_fold(const float* __restrict__ ssum, const float* __restrict__ ssq,
                       const float* __restrict__ g, const float* __restrict__ be,
                       const float* __restrict__ W, const float* __restrict__ b,
                       float* __restrict__ Wp, float* __restrict__ bp, int M, int Cn) {
    int j = threadIdx.x;
    if (j >= Cn) return;
    float fM = (float)M;
    float accb = b[j];
    for (int k = 0; k < 64; k++) {
        float mu = ssum[k] / fM;
        float var = ssq[k] / fM - mu * mu;
        float rstd = rsqrtf(var + BN_EPS);
        float ak = g[k] * rstd;
        float ck = be[k] - mu * ak;
        float w = W[k * Cn + j];
        Wp[k * Cn + j] = ak * w;
        accb = fmaf(ck, w, accb);
    }
    bp[j] = accb;
}

// ---------------------------------------------------------------------------
// fold BN2 into W3 [64x128], writing bf16 MFMA-B packed fragments directly
__global__ void k_fold_packed(const float* __restrict__ ssum, const float* __restrict__ ssq,
                              const float* __restrict__ g, const float* __restrict__ be,
                              const float* __restrict__ W, const float* __restrict__ b,
                              bf16_t* __restrict__ P, float* __restrict__ bp, int M) {
    int j = threadIdx.x;   // 0..127 output column
    if (j >= 128) return;
    float fM = (float)M;
    float accb = b[j];
    int n = j >> 4, jr = j & 15;
    for (int k = 0; k < 64; k++) {
        float mu = ssum[k] / fM;
        float var = ssq[k] / fM - mu * mu;
        float rstd = rsqrtf(var + BN_EPS);
        float ak = g[k] * rstd;
        float ck = be[k] - mu * ak;
        float w = W[k * 128 + j];
        accb = fmaf(ck, w, accb);
        int s = k >> 5, l = ((k >> 3) & 3) * 16 + jr, jj = k & 7;
        P[((size_t)((s * 8 + n) * 64 + l)) * 8 + jj] = (bf16_t)(ak * w);
    }
    bp[j] = accb;
}

// ---------------------------------------------------------------------------
// Pack W4/W5/W_in into bf16 MFMA-B fragment order
__global__ void k_pack(const float* __restrict__ W4, const float* __restrict__ W5,
                       const float* __restrict__ Win,
                       bf16_t* __restrict__ P1, bf16_t* __restrict__ P2, bf16_t* __restrict__ P0) {
    int tid = blockIdx.x * 256 + threadIdx.x;
    const float* W; bf16_t* P; int t;
    if (tid < 4096)      { W = W4;  P = P1; t = tid; }
    else if (tid < 6144) { W = W5;  P = P2; t = tid - 4096; }
    else if (tid < 7168) { W = Win; P = P0; t = tid - 6144; }
    else return;
    int l = t & 63;
    int sn = t >> 6;
    int col = (sn & 7) * 16 + (l & 15);
    int k0 = (sn >> 3) * 32 + (l >> 4) * 8;
    bf16_t* dst = P + (size_t)t * 8;
#pragma unroll
    for (int j = 0; j < 8; j++) dst[j] = (bf16_t)W[(size_t)(k0 + j) * 128 + col];
}

// ---------------------------------------------------------------------------
// k_two_gemm: out[M,128] = leaky(in[M,64] @ Pa + ba) @ Pb (+ bb)   (bf16 out)
__global__ __launch_bounds__(256) void k_two_gemm(
        const float* __restrict__ in, const bf16_t* __restrict__ Pa,
        const float* __restrict__ ba, const bf16_t* __restrict__ Pb,
        const float* __restrict__ bb, bf16_t* __restrict__ out, int M) {
    __shared__ bf16_t A[64 * 64];     // 8 KB
    __shared__ bf16_t C[64 * 128];    // 16 KB
    int tid = threadIdx.x;
    int base = blockIdx.x * 64;
    int valid = M - base; if (valid > 64) valid = 64;

    {   // stage A: thread covers row=tid>>2, 16 cols, f32->bf16, swizzled
        int r = tid >> 2, q = tid & 3;
        float4 v[4];
        if (r < valid) {
            const float4* src = reinterpret_cast<const float4*>(in + (size_t)(base + r) * 64 + q * 16);
#pragma unroll
            for (int i = 0; i < 4; i++) v[i] = src[i];
        } else {
#pragma unroll
            for (int i = 0; i < 4; i++) v[i] = make_float4(0.f, 0.f, 0.f, 0.f);
        }
        bf16x8 h0, h1;
#pragma unroll
        for (int i = 0; i < 2; i++) {
            h0[i * 4 + 0] = (bf16_t)v[i].x; h0[i * 4 + 1] = (bf16_t)v[i].y;
            h0[i * 4 + 2] = (bf16_t)v[i].z; h0[i * 4 + 3] = (bf16_t)v[i].w;
            h1[i * 4 + 0] = (bf16_t)v[2 + i].x; h1[i * 4 + 1] = (bf16_t)v[2 + i].y;
            h1[i * 4 + 2] = (bf16_t)v[2 + i].z; h1[i * 4 + 3] = (bf16_t)v[2 + i].w;
        }
        int xa = (r & 7) << 3;
        *reinterpret_cast<bf16x8*>(&A[r * 64 + ((q * 16) ^ xa)]) = h0;
        *reinterpret_cast<bf16x8*>(&A[r * 64 + ((q * 16 + 8) ^ xa)]) = h1;
    }
    __syncthreads();

    int w = tid >> 6, l = tid & 63;
    int lg = l >> 4, lr = l & 15;
    int xr = (lr & 7) << 3;

    // GEMM a: K=64 (2 k-steps), acc init ba, leaky -> C
    f32x4 acc[4][2];
#pragma unroll
    for (int t = 0; t < 2; t++) {
        float bv = ba[w * 32 + t * 16 + lr];
#pragma unroll
        for (int m = 0; m < 4; m++) acc[m][t] = (f32x4){bv, bv, bv, bv};
    }
#pragma unroll
    for (int s = 0; s < 2; s++) {
        bf16x8 a[4];
#pragma unroll
        for (int m = 0; m < 4; m++)
            a[m] = *reinterpret_cast<const bf16x8*>(&A[(m * 16 + lr) * 64 + (((s * 4 + lg) * 8) ^ xr)]);
#pragma unroll
        for (int t = 0; t < 2; t++) {
            bf16x8 b = *reinterpret_cast<const bf16x8*>(Pa + ((size_t)(s * 8 + w * 2 + t) * 64 + l) * 8);
#pragma unroll
            for (int m = 0; m < 4; m++)
                acc[m][t] = __builtin_amdgcn_mfma_f32_16x16x32_bf16(a[m], b, acc[m][t], 0, 0, 0);
        }
    }
#pragma unroll
    for (int m = 0; m < 4; m++)
#pragma unroll
        for (int t = 0; t < 2; t++)
#pragma unroll
            for (int rr = 0; rr < 4; rr++) {
                int row = m * 16 + lg * 4 + rr;
                int col = w * 32 + t * 16 + lr;
                C[row * 128 + (col ^ ((row & 7) << 3))] = (bf16_t)leaky(acc[m][t][rr]);
            }
    __syncthreads();

    // GEMM b: K=128 (4 k-steps), acc init bb (or 0)
    f32x4 acc2[4][2];
#pragma unroll
    for (int t = 0; t < 2; t++) {
        float bv = bb ? bb[w * 32 + t * 16 + lr] : 0.0f;
#pragma unroll
        for (int m = 0; m < 4; m++) acc2[m][t] = (f32x4){bv, bv, bv, bv};
    }
#pragma unroll
    for (int s = 0; s < 4; s++) {
        bf16x8 a[4];
#pragma unroll
        for (int m = 0; m < 4; m++)
            a[m] = *reinterpret_cast<const bf16x8*>(&C[(m * 16 + lr) * 128 + ((s * 32 + lg * 8) ^ xr)]);
#pragma unroll
        for (int t = 0; t < 2; t++) {
            bf16x8 b = *reinterpret_cast<const bf16x8*>(Pb + ((size_t)(s * 8 + w * 2 + t) * 64 + l) * 8);
#pragma unroll
            for (int m = 0; m < 4; m++)
                acc2[m][t] = __builtin_amdgcn_mfma_f32_16x16x32_bf16(a[m], b, acc2[m][t], 0, 0, 0);
        }
    }
    __syncthreads();   // all C reads complete before overwrite

    // overwrite C with acc2 (no activation), then coalesced 16B write-out
#pragma unroll
    for (int m = 0; m < 4; m++)
#pragma unroll
        for (int t = 0; t < 2; t++)
#pragma unroll
            for (int rr = 0; rr < 4; rr++) {
                int row = m * 16 + lg * 4 + rr;
                int col = w * 32 + t * 16 + lr;
                C[row * 128 + (col ^ ((row & 7) << 3))] = (bf16_t)acc2[m][t][rr];
            }
    __syncthreads();
#pragma unroll
    for (int i = 0; i < 4; i++) {
        int u = tid + i * 256;
        int row = u >> 4, seg = u & 15;
        if (row < valid) {
            bf16x8 val = *reinterpret_cast<const bf16x8*>(&C[row * 128 + ((seg * 8) ^ ((row & 7) << 3))]);
            *reinterpret_cast<bf16x8*>(&out[(size_t)(base + row) * 128 + seg * 8]) = val;
        }
    }
}

// ---------------------------------------------------------------------------
// k_gather_mean v2: one wave per output voxel; 2 points per instruction
// (lanes 0-31 cover point p, lanes 32-63 point p+1; bf16x4 per lane), x2 unroll.
__global__ __launch_bounds__(256) void k_gather_mean(
        const bf16_t* __restrict__ z1, const bf16_t* __restrict__ z2,
        const int2* __restrict__ csrAB, const int* __restrict__ rowstart,
        const int* __restrict__ cntI, bf16_t* __restrict__ meanB, int MO) {
    int w = threadIdx.x >> 6, l = threadIdx.x & 63;
    int half = l >> 5, sub = l & 31;
    int v = blockIdx.x * 4 + w;
    if (v >= MO) return;
    int cnt = cntI[v];
    int start = rowstart[v];
    float s[4] = {0.f, 0.f, 0.f, 0.f};
    int p = 0;
    for (; p + 4 <= cnt; p += 4) {
        int2 ea = csrAB[start + p + half];
        int2 eb = csrAB[start + p + 2 + half];
        bf16x4 za0 = *reinterpret_cast<const bf16x4*>(&z1[(size_t)ea.x * 128 + sub * 4]);
        bf16x4 zb0 = *reinterpret_cast<const bf16x4*>(&z2[(size_t)ea.y * 128 + sub * 4]);
        bf16x4 za1 = *reinterpret_cast<const bf16x4*>(&z1[(size_t)eb.x * 128 + sub * 4]);
        bf16x4 zb1 = *reinterpret_cast<const bf16x4*>(&z2[(size_t)eb.y * 128 + sub * 4]);
#pragma unroll
        for (int j = 0; j < 4; j++) {
            s[j] += leaky((float)za0[j] + (float)zb0[j]);
            s[j] += leaky((float)za1[j] + (float)zb1[j]);
        }
    }
    for (; p + 2 <= cnt; p += 2) {
        int2 e = csrAB[start + p + half];
        bf16x4 za = *reinterpret_cast<const bf16x4*>(&z1[(size_t)e.x * 128 + sub * 4]);
        bf16x4 zb = *reinterpret_cast<const bf16x4*>(&z2[(size_t)e.y * 128 + sub * 4]);
#pragma unroll
        for (int j = 0; j < 4; j++) s[j] += leaky((float)za[j] + (float)zb[j]);
    }
    if (p < cnt && half == 0) {
        int2 e = csrAB[start + p];
        bf16x4 za = *reinterpret_cast<const bf16x4*>(&z1[(size_t)e.x * 128 + sub * 4]);
        bf16x4 zb = *reinterpret_cast<const bf16x4*>(&z2[(size_t)e.y * 128 + sub * 4]);
#pragma unroll
        for (int j = 0; j < 4; j++) s[j] += leaky((float)za[j] + (float)zb[j]);
    }
    float sc = (cnt > 0) ? (1.0f / (float)cnt) : 0.0f;
    bf16x4 mv;
#pragma unroll
    for (int j = 0; j < 4; j++) {
        s[j] += __shfl_xor(s[j], 32);
        mv[j] = (bf16_t)(s[j] * sc);
    }
    if (half == 0)
        *reinterpret_cast<bf16x4*>(&meanB[(size_t)v * 128 + sub * 4]) = mv;
}

// ---------------------------------------------------------------------------
// k_vox2: out[MO,128] f32 = meanB[MO,128] @ P2 + b5, masked to 0 where cnt==0
__global__ __launch_bounds__(256) void k_vox2(
        const bf16_t* __restrict__ meanB, const int* __restrict__ cntI,
        const bf16_t* __restrict__ P2, const float* __restrict__ b5,
        float* __restrict__ outp, int MO) {
    int tid = threadIdx.x;
    int base = blockIdx.x * 64;
    int w = tid >> 6, l = tid & 63;
    int lg = l >> 4, lr = l & 15;
    f32x4 acc[4][2];
#pragma unroll
    for (int t = 0; t < 2; t++) {
        float bv = b5[w * 32 + t * 16 + lr];
#pragma unroll
        for (int m = 0; m < 4; m++) acc[m][t] = (f32x4){bv, bv, bv, bv};
    }
#pragma unroll
    for (int s = 0; s < 4; s++) {
        bf16x8 a[4];
#pragma unroll
        for (int m = 0; m < 4; m++) {
            int row = base + m * 16 + lr;
            a[m] = *reinterpret_cast<const bf16x8*>(&meanB[(size_t)row * 128 + (s * 4 + lg) * 8]);
        }
#pragma unroll
        for (int t = 0; t < 2; t++) {
            bf16x8 b = *reinterpret_cast<const bf16x8*>(P2 + ((size_t)(s * 8 + w * 2 + t) * 64 + l) * 8);
#pragma unroll
            for (int m = 0; m < 4; m++)
                acc[m][t] = __builtin_amdgcn_mfma_f32_16x16x32_bf16(a[m], b, acc[m][t], 0, 0, 0);
        }
    }
#pragma unroll
    for (int m = 0; m < 4; m++)
#pragma unroll
        for (int t = 0; t < 2; t++)
#pragma unroll
            for (int rr = 0; rr < 4; rr++) {
                int row = base + m * 16 + lg * 4 + rr;
                if (row < MO) {
                    float val = (cntI[row] > 0) ? acc[m][t][rr] : 0.0f;
                    outp[(size_t)row * 128 + w * 32 + t * 16 + lr] = val;
                }
            }
}

// ---------------------------------------------------------------------------
extern "C" void kernel_launch(void* const* d_in, const int* in_sizes, int n_in,
                              void* d_out, int out_size, void* d_ws, size_t ws_size,
                              hipStream_t stream) {
    const float* feat = (const float*)d_in[0];
    const int*   inv  = (const int*)d_in[1];
    const int*   cur  = (const int*)d_in[2];
    const int*   nxt  = (const int*)d_in[3];
    const float* W_in = (const float*)d_in[6];
    const float* b_in = (const float*)d_in[7];
    const float* W1   = (const float*)d_in[8];
    const float* b1   = (const float*)d_in[9];
    const float* g1   = (const float*)d_in[10];
    const float* be1  = (const float*)d_in[11];
    const float* W2   = (const float*)d_in[12];
    const float* b2   = (const float*)d_in[13];
    const float* g2   = (const float*)d_in[14];
    const float* be2  = (const float*)d_in[15];
    const float* W3   = (const float*)d_in[16];
    const float* b3   = (const float*)d_in[17];
    const float* W4   = (const float*)d_in[18];
    const float* b4   = (const float*)d_in[19];
    const float* W5   = (const float*)d_in[20];
    const float* b5   = (const float*)d_in[21];

    const int N  = in_sizes[0] / 64;
    const int NF = in_sizes[2];
    const int MO = out_size / 128;
    const int MD = MDV;   // n_down (device scalar; fixed problem size)

    float* ws = (float*)d_ws;
    size_t off = 0;
    // ---- zeroed region (stats + counters only) ----
    float* ssum1 = ws + off; off += 64;
    float* ssq1  = ws + off; off += 64;
    float* ssum2 = ws + off; off += 64;
    float* ssq2  = ws + off; off += 64;
    int* cntD    = (int*)(ws + off); off += (size_t)MD;
    int* cursorD = (int*)(ws + off); off += (size_t)MD;
    int* cntI    = (int*)(ws + off); off += (size_t)MO;
    int* cursor  = (int*)(ws + off); off += (size_t)MO;
    size_t zeroElems = off;
    // ---- non-zeroed ----
    float* dsum = ws + off; off += (size_t)MD * 64;
    float* t1   = ws + off; off += (size_t)MD * 64;
    float* t2   = ws + off; off += (size_t)MD * 64;
    float* Wp2  = ws + off; off += 64 * 64;
    float* bp2  = ws + off; off += 64;
    float* bp3  = ws + off; off += 128;
    int* rowstartD = (int*)(ws + off); off += (size_t)MD + 1;
    int* rowstart  = (int*)(ws + off); off += (size_t)MO + 1;
    int* csrD      = (int*)(ws + off); off += (size_t)N;
    off = (off + 1) & ~(size_t)1;   // 8B align for int2
    int2* csrAB    = (int2*)(ws + off); off += (size_t)NF * 2;
    bf16_t* bws = (bf16_t*)(ws + off);
    size_t boff = 0;
    bf16_t* z1    = bws + boff; boff += (size_t)N * 128;
    bf16_t* z2    = bws + boff; boff += (size_t)MD * 128;
    bf16_t* meanB = bws + boff; boff += (size_t)MO * 128 + 4096;  // +slack for tail OOB reads
    bf16_t* P0    = bws + boff; boff += 8192;
    bf16_t* P1    = bws + boff; boff += 32768;
    bf16_t* P2    = bws + boff; boff += 16384;
    bf16_t* P3    = bws + boff; boff += 8192;
    (void)ws_size; (void)n_in;

    hipMemsetAsync(d_ws, 0, zeroElems * sizeof(float), stream);

    int gmax = (NF > N ? NF : N);
    k_hist_both<<<(gmax + 255) / 256, 256, 0, stream>>>(inv, cntD, nxt, cntI, N, NF);
    k_scan_both<<<2, 1024, 0, stream>>>(cntD, rowstartD, MD, cntI, rowstart, MO);
    k_fill_both<<<(gmax + 255) / 256, 256, 0, stream>>>(inv, rowstartD, cursorD, csrD,
                                                        nxt, cur, rowstart, cursor,
                                                        csrAB, N, NF);

    // front MLP path (TLP-rich pool, then dense MLPs)
    k_downsum<<<(MD + 3) / 4, 256, 0, stream>>>(feat, csrD, rowstartD, cntD, dsum, MD);
    k_mlp64<<<512, 256, 0, stream>>>(dsum, W1, b1, t1, ssum1, ssq1, MD);
    k_fold<<<1, 64, 0, stream>>>(ssum1, ssq1, g1, be1, W2, b2, Wp2, bp2, MD, 64);
    k_mlp64<<<512, 256, 0, stream>>>(t1, Wp2, bp2, t2, ssum2, ssq2, MD);
    k_fold_packed<<<1, 128, 0, stream>>>(ssum2, ssq2, g2, be2, W3, b3, P3, bp3, MD);
    k_pack<<<28, 256, 0, stream>>>(W4, W5, W_in, P1, P2, P0);

    // z2 = leaky(t2 @ Wp3 + bp3) @ W4_bot          [MD x 128], L2-resident
    k_two_gemm<<<(MD + 63) / 64, 256, 0, stream>>>(t2, P3, bp3, P1 + 16384, nullptr, z2, MD);
    // z1 = leaky(feat @ Win + bin) @ W4_top + b4   [N x 128]
    k_two_gemm<<<(N + 63) / 64, 256, 0, stream>>>(feat, P0, b_in, P1, b4, z1, N);

    // per-voxel paired gather-mean of leaky(z1+z2)
    k_gather_mean<<<(MO + 3) / 4, 256, 0, stream>>>(z1, z2, csrAB, rowstart, cntI, meanB, MO);
    // out = meanB @ W5 + b5 (masked where empty)
    k_vox2<<<(MO + 63) / 64, 256, 0, stream>>>(meanB, cntI, P2, b5, (float*)d_out, MO);
}